// Round 2
// baseline (382.739 us; speedup 1.0000x reference)
//
#include <hip/hip_runtime.h>
#include <cstdint>
#include <cstddef>

// ---------------- types / helpers ----------------
typedef __attribute__((ext_vector_type(8))) __bf16 bf16x8;
typedef __attribute__((ext_vector_type(4))) float f32x4;
typedef __attribute__((ext_vector_type(16))) float f32x16;

__device__ __forceinline__ unsigned short f2b(float x) {
    uint32_t u = __float_as_uint(x);
    u += 0x7FFFu + ((u >> 16) & 1u);   // RNE
    return (unsigned short)(u >> 16);
}
__device__ __forceinline__ float b2f(unsigned short h) {
    return __uint_as_float(((uint32_t)h) << 16);
}

#define L_SEQ 512
#define N_AA 21
#define DDIM 128
#define NCOL 2688        // 21*128
#define NSEQ 512         // 256 + 256
#define TBSTRIDE 448     // Tb row stride (u16), 441 used
#define KTOT 10752       // 512*21
#define ZCH 12           // k-chunks
#define KBTOT 672        // 10752/16 k-subtiles
#define KBCH 56          // 672/12 k-subtiles per chunk

// block-range sizes inside prep_kernel
#define PB_WBZ   14112   // 84*672/4 fragments
#define PB_EINIT 5376
#define PB_REPACK 1024
#define PB_WBUILD 1024
#define PB_ABZ   2688    // 16*672/4 fragments
#define PB_TOTAL (PB_WBZ + PB_EINIT + PB_REPACK + PB_WBUILD + PB_ABZ)

// ---------------- kernel 1: fused prologue ----------------
// Independent sub-jobs, dispatched by blockIdx range:
//   [0, 14112)     : W fp32 -> Wbz bf16 fragment-swizzled
//   [+5376)        : E init with bias
//   [+1024)        : X1/X2 int32 -> X8 u8
//   [+1024)        : w32 = sigmoid(wm), wswz = bf16 MFMA-frag order
//   [+2688)        : one-hot A -> Abz bf16 fragment-swizzled (reads X1/X2)
__global__ __launch_bounds__(256) void prep_kernel(const int* X1, const int* X2,
                                                   const float* W, const float* bvec, const float* wp,
                                                   uint8_t* X8,
                                                   float* w32, unsigned short* wswz,
                                                   float* E, unsigned short* Wbz, unsigned short* Abz) {
    int bid = blockIdx.x;
    int t = threadIdx.x;
    if (bid < PB_WBZ) {
        // Wbz fragment (cb,kb): lane (hf,lr) holds W[kb*16+hf*8+j][cb*32+lr], j=0..7
        int f = bid * 4 + (t >> 6);
        int lane = t & 63, lr = lane & 31, hf = lane >> 5;
        int cb = f / KBTOT, kb = f - cb * KBTOT;
        const float* src = W + (size_t)(kb * 16 + hf * 8) * NCOL + cb * 32 + lr;
        union { uint4 q; unsigned short s[8]; } o;
#pragma unroll
        for (int j = 0; j < 8; ++j) o.s[j] = f2b(src[(size_t)j * NCOL]);
        *(uint4*)&Wbz[(size_t)f * 512 + lane * 8] = o.q;
        return;
    }
    bid -= PB_WBZ;
    if (bid < PB_EINIT) {
        int e = bid * 256 + t;             // 1,376,256
        E[e] = bvec[e % NCOL];
        return;
    }
    bid -= PB_EINIT;
    if (bid < PB_REPACK) {
        int e = bid * 256 + t;             // 262,144
        if (e < 131072) X8[e] = (uint8_t)X1[e];
        else            X8[e] = (uint8_t)X2[e - 131072];
        return;
    }
    bid -= PB_REPACK;
    if (bid < PB_WBUILD) {
        int e = bid * 256 + t;             // 262,144 = 512*512
        int p = e >> 9, q = e & 511;
        float x = 0.0f;
        if (p > q)      x = wp[p * (p - 1) / 2 + q];
        else if (p < q) x = wp[q * (q - 1) / 2 + p];
        float s = 1.0f / (1.0f + expf(-x));
        w32[e] = s;
        int nb = p >> 5, lr = p & 31;
        int kb = q >> 4, hf = (q >> 3) & 1, j = q & 7;
        wswz[(size_t)((nb * 32 + kb) * 512) + (hf * 32 + lr) * 8 + j] = f2b(s);
        return;
    }
    bid -= PB_WBUILD;
    {
        // Abz fragment (mb,kb): lane (hf,lr) holds onehot(X[mb*32+lr], k=kb*16+hf*8+j)
        int f = bid * 4 + (t >> 6);        // 0..10751
        int lane = t & 63, lr = lane & 31, hf = lane >> 5;
        int mb = f / KBTOT, kb = f - mb * KBTOT;
        int m = mb * 32 + lr;
        const int* Xrow = (m < 256) ? (X1 + (size_t)m * L_SEQ) : (X2 + (size_t)(m - 256) * L_SEQ);
        int k0 = kb * 16 + hf * 8;
        union { uint4 q; unsigned short s[8]; } o;
#pragma unroll
        for (int j = 0; j < 8; ++j) {
            int k = k0 + j;
            int l = k / N_AA;
            int aa = k - l * N_AA;
            o.s[j] = (Xrow[l] == aa) ? (unsigned short)0x3F80u : (unsigned short)0u;
        }
        *(uint4*)&Abz[(size_t)f * 512 + lane * 8] = o.q;
    }
}

// ---------------- kernel 2: E += A @ W, pure dense MFMA, both operands pre-swizzled ----
// 1008 blocks (21 c-tiles x 4 m-tiles x 12 k-chunks), XCD-swizzled. 4 waves/block.
// Wave: 64m x 64c (2x2 fragments), 56 K-subtiles of 16. Zero VALU in inner loop.
__global__ __launch_bounds__(256, 4) void e_mfma_v2(const unsigned short* Abz, const unsigned short* Wbz, float* E) {
    int lin = blockIdx.x;
    int s = ((lin & 7) * 126) + (lin >> 3);   // bijective XCD swizzle (1008 % 8 == 0)
    int cx = s % 21;
    int rem = s / 21;
    int my = rem & 3;
    int kz = rem >> 2;

    int t = threadIdx.x, wid = t >> 6, lane = t & 63;
    int lr = lane & 31, hf = lane >> 5;

    int kb0 = kz * KBCH;
    int mb0 = my * 4 + (wid & 1) * 2;        // m-fragment index (32-row units), 0..15
    int cb0 = cx * 4 + (wid >> 1) * 2;       // c-fragment index (32-col units), 0..83

    const unsigned short* Ap0 = Abz + ((size_t)(mb0 * KBTOT + kb0)) * 512 + lane * 8;
    const unsigned short* Ap1 = Ap0 + (size_t)KBTOT * 512;
    const unsigned short* Bp0 = Wbz + ((size_t)(cb0 * KBTOT + kb0)) * 512 + lane * 8;
    const unsigned short* Bp1 = Bp0 + (size_t)KBTOT * 512;

    f32x16 acc00, acc01, acc10, acc11;
#pragma unroll
    for (int r = 0; r < 16; ++r) { acc00[r] = 0.f; acc01[r] = 0.f; acc10[r] = 0.f; acc11[r] = 0.f; }

#pragma unroll 2
    for (int kb = 0; kb < KBCH; ++kb) {
        bf16x8 a0 = *(const bf16x8*)(Ap0 + kb * 512);
        bf16x8 a1 = *(const bf16x8*)(Ap1 + kb * 512);
        bf16x8 b0 = *(const bf16x8*)(Bp0 + kb * 512);
        bf16x8 b1 = *(const bf16x8*)(Bp1 + kb * 512);
        acc00 = __builtin_amdgcn_mfma_f32_32x32x16_bf16(a0, b0, acc00, 0, 0, 0);
        acc01 = __builtin_amdgcn_mfma_f32_32x32x16_bf16(a0, b1, acc01, 0, 0, 0);
        acc10 = __builtin_amdgcn_mfma_f32_32x32x16_bf16(a1, b0, acc10, 0, 0, 0);
        acc11 = __builtin_amdgcn_mfma_f32_32x32x16_bf16(a1, b1, acc11, 0, 0, 0);
    }

#pragma unroll
    for (int r = 0; r < 16; ++r) {
        int row = (r & 3) + 8 * (r >> 2) + 4 * hf;
        float* base = E + (size_t)(mb0 * 32 + row) * NCOL + cb0 * 32 + lr;
        atomicAdd(base, acc00[r]);
        atomicAdd(base + 32, acc01[r]);
        atomicAdd(base + (size_t)32 * NCOL, acc10[r]);
        atomicAdd(base + (size_t)32 * NCOL + 32, acc11[r]);
    }
}

// ---------------- kernel 3: T[n] = E[n] @ E[n]^T (21x21) -> bf16 Tb (0.5x) + fp32 diag ----
__global__ __launch_bounds__(256) void t_kernel(const float* E, unsigned short* Tb, float* Tdiag) {
    __shared__ float4 Es4[21 * 33];
    int t = threadIdx.x, n = blockIdx.x;
    for (int e = t; e < 21 * 32; e += 256) {
        int r = e >> 5, d = e & 31;
        Es4[r * 33 + d] = *(const float4*)(E + (size_t)n * NCOL + r * 128 + d * 4);
    }
    __syncthreads();
    for (int e = t; e < 441; e += 256) {
        int r = e / 21, c = e - r * 21;
        const float4* ar = &Es4[r * 33];
        const float4* br = &Es4[c * 33];
        float s = 0.f;
#pragma unroll 8
        for (int d = 0; d < 32; ++d) {
            float4 a = ar[d], b = br[d];
            s += a.x * b.x + a.y * b.y + a.z * b.z + a.w * b.w;
        }
        Tb[(size_t)n * TBSTRIDE + e] = f2b(0.5f * s);
        if (r == c) Tdiag[n * 24 + r] = s;
    }
}

// ---------------- kernel 4: kinv, n-tile 4 (w32 row reuse) ----------------
__global__ __launch_bounds__(256) void k_kernel(const uint8_t* X8, const float* Tdiag, const float* w32, float* kinv) {
    __shared__ __align__(16) float dvec[4][512];
    __shared__ float Td[4][21];
    __shared__ float red[4][256];
    int t = threadIdx.x, n0 = blockIdx.x * 4;
    if (t < 84) Td[t / 21][t % 21] = Tdiag[(size_t)(n0 + t / 21) * 24 + (t % 21)];
    __syncthreads();
    for (int e = t; e < 2048; e += 256) {
        int nn = e >> 9, l = e & 511;
        dvec[nn][l] = Td[nn][X8[(size_t)(n0 + nn) * 512 + l]];
    }
    __syncthreads();
    float p0 = 0.f, p1 = 0.f, p2 = 0.f, p3 = 0.f;
    for (int p = t; p < 512; p += 256) {
        const float4* wr4 = (const float4*)(w32 + (size_t)p * 512);
        float d0 = 0.f, d1 = 0.f, d2 = 0.f, d3 = 0.f;
        for (int q = 0; q < 128; ++q) {
            float4 wv = wr4[q];
            float4 a = ((const float4*)dvec[0])[q];
            float4 b = ((const float4*)dvec[1])[q];
            float4 c = ((const float4*)dvec[2])[q];
            float4 d = ((const float4*)dvec[3])[q];
            d0 += wv.x * a.x + wv.y * a.y + wv.z * a.z + wv.w * a.w;
            d1 += wv.x * b.x + wv.y * b.y + wv.z * b.z + wv.w * b.w;
            d2 += wv.x * c.x + wv.y * c.y + wv.z * c.z + wv.w * c.w;
            d3 += wv.x * d.x + wv.y * d.y + wv.z * d.z + wv.w * d.w;
        }
        p0 += dvec[0][p] * d0;
        p1 += dvec[1][p] * d1;
        p2 += dvec[2][p] * d2;
        p3 += dvec[3][p] * d3;
    }
    red[0][t] = p0; red[1][t] = p1; red[2][t] = p2; red[3][t] = p3;
    __syncthreads();
    for (int s = 128; s > 0; s >>= 1) {
        if (t < s) {
            red[0][t] += red[0][t + s];
            red[1][t] += red[1][t + s];
            red[2][t] += red[2][t + s];
            red[3][t] += red[3][t + s];
        }
        __syncthreads();
    }
    if (t < 4) kinv[n0 + t] = 1.0f / sqrtf(red[t][0]);
}

// ---------------- kernel 5: main pair GEMM — 8 waves (512 thr), bf16 Tb staging ----------
__global__ __launch_bounds__(512, 6) void k4_kernel(const uint8_t* X8, const unsigned short* Tb,
                                                    const unsigned short* wswz, const float* kinv,
                                                    const float* Ainp, float* out) {
    __shared__ unsigned short Sh[32 * 520];
    __shared__ unsigned short Ts1h[4 * TBSTRIDE];
    __shared__ unsigned short Ts2h[8 * TBSTRIDE];
    __shared__ unsigned short A21[4 * 512];
    __shared__ uint8_t Xs2[8 * 512];
    __shared__ float Kacc[8][32];

    int t = threadIdx.x;
    int i0 = blockIdx.x * 4;
    int j0 = blockIdx.y * 8;

    for (int e = t; e < 4 * 512; e += 512)
        A21[e] = (unsigned short)(21 * X8[(size_t)(i0 + (e >> 9)) * 512 + (e & 511)]);
    {
        const uint32_t* s2 = (const uint32_t*)(X8 + (size_t)(256 + j0) * 512);
        uint32_t* d2 = (uint32_t*)Xs2;
        for (int e = t; e < 1024; e += 512) d2[e] = s2[e];
    }
    {
        // Tb rows are already 0.5*T in bf16 — straight u32 copies (448 u16 = 224 u32 per row)
        uint32_t* d1 = (uint32_t*)Ts1h;
        for (int e = t; e < 4 * 224; e += 512) {
            int r = e / 224, w = e - r * 224;
            d1[e] = ((const uint32_t*)(Tb + (size_t)(i0 + r) * TBSTRIDE))[w];
        }
        uint32_t* d2 = (uint32_t*)Ts2h;
        for (int e = t; e < 8 * 224; e += 512) {
            int r = e / 224, w = e - r * 224;
            d2[e] = ((const uint32_t*)(Tb + (size_t)(256 + j0 + r) * TBSTRIDE))[w];
        }
    }
    __syncthreads();

    // build S tile: 4 elems per thread-iter, packed u64 write
    for (int e4 = t; e4 < 32 * 128; e4 += 512) {
        int pr = e4 >> 7, p = (e4 & 127) * 4;
        int ti = pr >> 3, tj = pr & 7;
        uint64_t a4 = *(const uint64_t*)&A21[ti * 512 + p];   // 4 u16 (a*21)
        uint32_t b4 = *(const uint32_t*)&Xs2[tj * 512 + p];   // 4 u8
        const unsigned short* T1 = &Ts1h[ti * TBSTRIDE];
        const unsigned short* T2 = &Ts2h[tj * TBSTRIDE];
        uint64_t outw = 0;
#pragma unroll
        for (int u = 0; u < 4; ++u) {
            int idx = (int)((a4 >> (16 * u)) & 0xFFFFu) + (int)((b4 >> (8 * u)) & 0xFFu);
            float v = b2f(T1[idx]) + b2f(T2[idx]);
            outw |= (uint64_t)f2b(v) << (16 * u);
        }
        *(uint64_t*)&Sh[pr * 520 + p] = outw;
    }
    __syncthreads();

    int wid = t >> 6, lane = t & 63;
    int lr = lane & 31, hf = lane >> 5;
    int n_base = wid * 64;

    const unsigned short* Sa = &Sh[lr * 520 + hf * 8];
    const unsigned short* Bz0 = wswz + (size_t)((wid * 2 + 0) * 32) * 512 + lane * 8;
    const unsigned short* Bz1 = wswz + (size_t)((wid * 2 + 1) * 32) * 512 + lane * 8;

    f32x16 acc0, acc1;
#pragma unroll
    for (int j = 0; j < 16; ++j) { acc0[j] = 0.f; acc1[j] = 0.f; }

#pragma unroll 2
    for (int kt = 0; kt < 32; ++kt) {
        bf16x8 av = *(const bf16x8*)(Sa + kt * 16);
        bf16x8 bv0 = *(const bf16x8*)(Bz0 + kt * 512);
        bf16x8 bv1 = *(const bf16x8*)(Bz1 + kt * 512);
        acc0 = __builtin_amdgcn_mfma_f32_32x32x16_bf16(av, bv0, acc0, 0, 0, 0);
        acc1 = __builtin_amdgcn_mfma_f32_32x32x16_bf16(av, bv1, acc1, 0, 0, 0);
    }

    float prow[16];
#pragma unroll
    for (int r = 0; r < 16; ++r) {
        int row = (r & 3) + 8 * (r >> 2) + 4 * hf;
        float v = acc0[r] * b2f(Sh[row * 520 + (n_base + lr)]);
        v      += acc1[r] * b2f(Sh[row * 520 + (n_base + 32 + lr)]);
        prow[r] = v;
    }
#pragma unroll
    for (int r = 0; r < 16; ++r) {
        float v = prow[r];
        v += __shfl_xor(v, 1);
        v += __shfl_xor(v, 2);
        v += __shfl_xor(v, 4);
        v += __shfl_xor(v, 8);
        v += __shfl_xor(v, 16);
        if (lr == 0) {
            int row = (r & 3) + 8 * (r >> 2) + 4 * hf;
            Kacc[wid][row] = v;
        }
    }
    __syncthreads();

    if (t < 32) {
        float K = Kacc[0][t] + Kacc[1][t] + Kacc[2][t] + Kacc[3][t]
                + Kacc[4][t] + Kacc[5][t] + Kacc[6][t] + Kacc[7][t];
        int ti = t >> 3, tj = t & 7;
        int i = i0 + ti, j = j0 + tj;
        float a0 = Ainp[0];
        out[i * 256 + j] = a0 * a0 * K * kinv[i] * kinv[256 + j];
    }
}

// ---------------- launcher ----------------
extern "C" void kernel_launch(void* const* d_in, const int* in_sizes, int n_in,
                              void* d_out, int out_size, void* d_ws, size_t ws_size,
                              hipStream_t stream) {
    const int*   X1 = (const int*)d_in[0];
    const int*   X2 = (const int*)d_in[1];
    const float* W  = (const float*)d_in[2];
    const float* b  = (const float*)d_in[3];
    const float* wp = (const float*)d_in[4];
    const float* a  = (const float*)d_in[5];
    float* out = (float*)d_out;

    char* ws = (char*)d_ws;
    float*          E     = (float*)(ws + 0);                  //  5,505,024
    unsigned short* Tb    = (unsigned short*)(ws + 5505024);   //    458,752
    float*          Tdiag = (float*)(ws + 5963776);            //     49,152
    float*          w32   = (float*)(ws + 6012928);            //  1,048,576
    unsigned short* wswz  = (unsigned short*)(ws + 7061504);   //    524,288
    float*          kinv  = (float*)(ws + 7585792);            //      2,048
    uint8_t*        X8    = (uint8_t*)(ws + 7587840);          //    262,144
    unsigned short* Abz   = (unsigned short*)(ws + 7849984);   // 11,010,048
    unsigned short* Wbz   = (unsigned short*)(ws + 18860032);  // 57,802,752 (end 76,662,784)

    prep_kernel<<<PB_TOTAL, 256, 0, stream>>>(X1, X2, W, b, wp, X8, w32, wswz, E, Wbz, Abz);
    e_mfma_v2<<<1008, 256, 0, stream>>>(Abz, Wbz, E);
    t_kernel<<<512, 256, 0, stream>>>(E, Tb, Tdiag);
    k_kernel<<<128, 256, 0, stream>>>(X8, Tdiag, w32, kinv);
    k4_kernel<<<dim3(64, 32), 512, 0, stream>>>(X8, Tb, wswz, kinv, a, out);
}

// Round 3
// 376.345 us; speedup vs baseline: 1.0170x; 1.0170x over previous
//
#include <hip/hip_runtime.h>
#include <cstdint>
#include <cstddef>

// ---------------- types / helpers ----------------
typedef __attribute__((ext_vector_type(8))) __bf16 bf16x8;
typedef __attribute__((ext_vector_type(4))) float f32x4;
typedef __attribute__((ext_vector_type(16))) float f32x16;

__device__ __forceinline__ unsigned short f2b(float x) {
    uint32_t u = __float_as_uint(x);
    u += 0x7FFFu + ((u >> 16) & 1u);   // RNE
    return (unsigned short)(u >> 16);
}
__device__ __forceinline__ float b2f(unsigned short h) {
    return __uint_as_float(((uint32_t)h) << 16);
}

// async global->LDS, 16B per lane. LDS dest is wave-uniform base (+lane*16 by HW).
__device__ __forceinline__ void gl16(const unsigned short* g, unsigned short* l) {
    __builtin_amdgcn_global_load_lds((const __attribute__((address_space(1))) uint32_t*)g,
                                     (__attribute__((address_space(3))) uint32_t*)l, 16, 0, 0);
}

#define L_SEQ 512
#define N_AA 21
#define DDIM 128
#define NCOL 2688        // 21*128
#define NSEQ 512         // 256 + 256
#define TBSTRIDE 448     // Tb row stride (u16), 441 used
#define KTOT 10752       // 512*21
#define ZCH 12           // k-chunks
#define KBTOT 672        // 10752/16 k-subtiles
#define KBCH 56          // 672/12 k-subtiles per chunk

// block-range sizes inside prep_kernel
#define PB_WBZ   14112   // 84*672/4 fragments
#define PB_EINIT 5376
#define PB_REPACK 1024
#define PB_WBUILD 1024
#define PB_ABZ   2688    // 16*672/4 fragments
#define PB_TOTAL (PB_WBZ + PB_EINIT + PB_REPACK + PB_WBUILD + PB_ABZ)

// ---------------- kernel 1: fused prologue ----------------
__global__ __launch_bounds__(256) void prep_kernel(const int* X1, const int* X2,
                                                   const float* W, const float* bvec, const float* wp,
                                                   uint8_t* X8,
                                                   float* w32, unsigned short* wswz,
                                                   float* E, unsigned short* Wbz, unsigned short* Abz) {
    int bid = blockIdx.x;
    int t = threadIdx.x;
    if (bid < PB_WBZ) {
        // Wbz fragment (cb,kb): lane (hf,lr) holds W[kb*16+hf*8+j][cb*32+lr], j=0..7
        int f = bid * 4 + (t >> 6);
        int lane = t & 63, lr = lane & 31, hf = lane >> 5;
        int cb = f / KBTOT, kb = f - cb * KBTOT;
        const float* src = W + (size_t)(kb * 16 + hf * 8) * NCOL + cb * 32 + lr;
        union { uint4 q; unsigned short s[8]; } o;
#pragma unroll
        for (int j = 0; j < 8; ++j) o.s[j] = f2b(src[(size_t)j * NCOL]);
        *(uint4*)&Wbz[(size_t)f * 512 + lane * 8] = o.q;
        return;
    }
    bid -= PB_WBZ;
    if (bid < PB_EINIT) {
        int e = bid * 256 + t;             // 1,376,256
        E[e] = bvec[e % NCOL];
        return;
    }
    bid -= PB_EINIT;
    if (bid < PB_REPACK) {
        int e = bid * 256 + t;             // 262,144
        if (e < 131072) X8[e] = (uint8_t)X1[e];
        else            X8[e] = (uint8_t)X2[e - 131072];
        return;
    }
    bid -= PB_REPACK;
    if (bid < PB_WBUILD) {
        int e = bid * 256 + t;             // 262,144 = 512*512
        int p = e >> 9, q = e & 511;
        float x = 0.0f;
        if (p > q)      x = wp[p * (p - 1) / 2 + q];
        else if (p < q) x = wp[q * (q - 1) / 2 + p];
        float s = 1.0f / (1.0f + expf(-x));
        w32[e] = s;
        int nb = p >> 5, lr = p & 31;
        int kb = q >> 4, hf = (q >> 3) & 1, j = q & 7;
        wswz[(size_t)((nb * 32 + kb) * 512) + (hf * 32 + lr) * 8 + j] = f2b(s);
        return;
    }
    bid -= PB_WBUILD;
    {
        // Abz fragment (mb,kb): lane (hf,lr) holds onehot(X[mb*32+lr], k=kb*16+hf*8+j)
        int f = bid * 4 + (t >> 6);        // 0..10751
        int lane = t & 63, lr = lane & 31, hf = lane >> 5;
        int mb = f / KBTOT, kb = f - mb * KBTOT;
        int m = mb * 32 + lr;
        const int* Xrow = (m < 256) ? (X1 + (size_t)m * L_SEQ) : (X2 + (size_t)(m - 256) * L_SEQ);
        int k0 = kb * 16 + hf * 8;
        union { uint4 q; unsigned short s[8]; } o;
#pragma unroll
        for (int j = 0; j < 8; ++j) {
            int k = k0 + j;
            int l = k / N_AA;
            int aa = k - l * N_AA;
            o.s[j] = (Xrow[l] == aa) ? (unsigned short)0x3F80u : (unsigned short)0u;
        }
        *(uint4*)&Abz[(size_t)f * 512 + lane * 8] = o.q;
    }
}

// ---------------- kernel 2: E += A @ W — LDS-staged pipelined MFMA (depth-4 vmcnt) -----
// 1008 blocks (21 c x 4 m x 12 k), XCD-swizzled, 4 waves. Per K-step the block stages its
// 8 UNIQUE fragments (4 A + 4 B, 8 KB) once via global_load_lds into a 4-deep ring;
// counted vmcnt(6) keeps 3 K-steps of loads in flight across raw s_barriers.
__global__ __launch_bounds__(256, 4) void e_mfma_v3(const unsigned short* Abz, const unsigned short* Wbz, float* E) {
    __shared__ unsigned short lds[4 * 8 * 512];   // 4 bufs x 8 frags x 1024 B = 32 KB

    int lin = blockIdx.x;
    int s = ((lin & 7) * 126) + (lin >> 3);   // bijective XCD swizzle (1008 % 8 == 0)
    int cx = s % 21;
    int rem = s / 21;
    int my = rem & 3;
    int kz = rem >> 2;

    int t = threadIdx.x, wid = t >> 6, lane = t & 63;
    int lr = lane & 31, hf = lane >> 5;
    int kb0 = kz * KBCH;

    // per-wave staging sources (global, per-lane addr) and LDS dests (wave-uniform)
    const unsigned short* Aw = Abz + ((size_t)((my * 4 + wid) * KBTOT + kb0)) * 512 + lane * 8;
    const unsigned short* Bw = Wbz + ((size_t)((cx * 4 + wid) * KBTOT + kb0)) * 512 + lane * 8;
    unsigned short* La = &lds[wid * 512];
    unsigned short* Lb = &lds[(4 + wid) * 512];

#define STG(buf_, kb_) do { \
        gl16(Aw + (size_t)(kb_) * 512, La + (buf_) * 4096); \
        gl16(Bw + (size_t)(kb_) * 512, Lb + (buf_) * 4096); \
    } while (0)

    int alo = (wid & 1) * 2;          // A frag slots this wave consumes
    int blo = 4 + (wid >> 1) * 2;     // B frag slots

    f32x16 acc00, acc01, acc10, acc11;
#pragma unroll
    for (int r = 0; r < 16; ++r) { acc00[r] = 0.f; acc01[r] = 0.f; acc10[r] = 0.f; acc11[r] = 0.f; }

#define COMPUTE(kb_) do { \
        const unsigned short* base = &lds[((kb_) & 3) * 4096]; \
        bf16x8 a0 = *(const bf16x8*)(base + (alo + 0) * 512 + lane * 8); \
        bf16x8 a1 = *(const bf16x8*)(base + (alo + 1) * 512 + lane * 8); \
        bf16x8 b0 = *(const bf16x8*)(base + (blo + 0) * 512 + lane * 8); \
        bf16x8 b1 = *(const bf16x8*)(base + (blo + 1) * 512 + lane * 8); \
        acc00 = __builtin_amdgcn_mfma_f32_32x32x16_bf16(a0, b0, acc00, 0, 0, 0); \
        acc01 = __builtin_amdgcn_mfma_f32_32x32x16_bf16(a0, b1, acc01, 0, 0, 0); \
        acc10 = __builtin_amdgcn_mfma_f32_32x32x16_bf16(a1, b0, acc10, 0, 0, 0); \
        acc11 = __builtin_amdgcn_mfma_f32_32x32x16_bf16(a1, b1, acc11, 0, 0, 0); \
    } while (0)

    // prologue: stage kb=0,1,2 (6 loads/wave outstanding)
    STG(0, 0); STG(1, 1); STG(2, 2);

#pragma unroll 1
    for (int kb = 0; kb < KBCH - 3; ++kb) {
        STG((kb + 3) & 3, kb + 3);                      // overwrite buffer read at kb-1 (fenced below)
        asm volatile("s_waitcnt vmcnt(6)" ::: "memory"); // own kb loads landed; 3 steps stay in flight
        __builtin_amdgcn_s_barrier();                    // all waves' kb loads landed
        __builtin_amdgcn_sched_barrier(0);
        COMPUTE(kb);
        __builtin_amdgcn_sched_barrier(0);
        __builtin_amdgcn_s_barrier();                    // all waves done reading buf[kb&3] before restage
    }
    // tail: kb = 53, 54, 55 (no more staging)
    asm volatile("s_waitcnt vmcnt(4)" ::: "memory");
    __builtin_amdgcn_s_barrier();
    __builtin_amdgcn_sched_barrier(0);
    COMPUTE(53);
    asm volatile("s_waitcnt vmcnt(2)" ::: "memory");
    __builtin_amdgcn_s_barrier();
    __builtin_amdgcn_sched_barrier(0);
    COMPUTE(54);
    asm volatile("s_waitcnt vmcnt(0)" ::: "memory");
    __builtin_amdgcn_s_barrier();
    __builtin_amdgcn_sched_barrier(0);
    COMPUTE(55);

#undef STG
#undef COMPUTE

    int mb0 = my * 4 + (wid & 1) * 2;        // m-fragment index (32-row units)
    int cb0 = cx * 4 + (wid >> 1) * 2;       // c-fragment index (32-col units)
#pragma unroll
    for (int r = 0; r < 16; ++r) {
        int row = (r & 3) + 8 * (r >> 2) + 4 * hf;
        float* base = E + (size_t)(mb0 * 32 + row) * NCOL + cb0 * 32 + lr;
        atomicAdd(base, acc00[r]);
        atomicAdd(base + 32, acc01[r]);
        atomicAdd(base + (size_t)32 * NCOL, acc10[r]);
        atomicAdd(base + (size_t)32 * NCOL + 32, acc11[r]);
    }
}

// ---------------- kernel 3: T[n] = E[n] @ E[n]^T (21x21) -> bf16 Tb (0.5x) + fp32 diag ----
__global__ __launch_bounds__(256) void t_kernel(const float* E, unsigned short* Tb, float* Tdiag) {
    __shared__ float4 Es4[21 * 33];
    int t = threadIdx.x, n = blockIdx.x;
    for (int e = t; e < 21 * 32; e += 256) {
        int r = e >> 5, d = e & 31;
        Es4[r * 33 + d] = *(const float4*)(E + (size_t)n * NCOL + r * 128 + d * 4);
    }
    __syncthreads();
    for (int e = t; e < 441; e += 256) {
        int r = e / 21, c = e - r * 21;
        const float4* ar = &Es4[r * 33];
        const float4* br = &Es4[c * 33];
        float s = 0.f;
#pragma unroll 8
        for (int d = 0; d < 32; ++d) {
            float4 a = ar[d], b = br[d];
            s += a.x * b.x + a.y * b.y + a.z * b.z + a.w * b.w;
        }
        Tb[(size_t)n * TBSTRIDE + e] = f2b(0.5f * s);
        if (r == c) Tdiag[n * 24 + r] = s;
    }
}

// ---------------- kernel 4: kinv, n-tile 4 (w32 row reuse) ----------------
__global__ __launch_bounds__(256) void k_kernel(const uint8_t* X8, const float* Tdiag, const float* w32, float* kinv) {
    __shared__ __align__(16) float dvec[4][512];
    __shared__ float Td[4][21];
    __shared__ float red[4][256];
    int t = threadIdx.x, n0 = blockIdx.x * 4;
    if (t < 84) Td[t / 21][t % 21] = Tdiag[(size_t)(n0 + t / 21) * 24 + (t % 21)];
    __syncthreads();
    for (int e = t; e < 2048; e += 256) {
        int nn = e >> 9, l = e & 511;
        dvec[nn][l] = Td[nn][X8[(size_t)(n0 + nn) * 512 + l]];
    }
    __syncthreads();
    float p0 = 0.f, p1 = 0.f, p2 = 0.f, p3 = 0.f;
    for (int p = t; p < 512; p += 256) {
        const float4* wr4 = (const float4*)(w32 + (size_t)p * 512);
        float d0 = 0.f, d1 = 0.f, d2 = 0.f, d3 = 0.f;
        for (int q = 0; q < 128; ++q) {
            float4 wv = wr4[q];
            float4 a = ((const float4*)dvec[0])[q];
            float4 b = ((const float4*)dvec[1])[q];
            float4 c = ((const float4*)dvec[2])[q];
            float4 d = ((const float4*)dvec[3])[q];
            d0 += wv.x * a.x + wv.y * a.y + wv.z * a.z + wv.w * a.w;
            d1 += wv.x * b.x + wv.y * b.y + wv.z * b.z + wv.w * b.w;
            d2 += wv.x * c.x + wv.y * c.y + wv.z * c.z + wv.w * c.w;
            d3 += wv.x * d.x + wv.y * d.y + wv.z * d.z + wv.w * d.w;
        }
        p0 += dvec[0][p] * d0;
        p1 += dvec[1][p] * d1;
        p2 += dvec[2][p] * d2;
        p3 += dvec[3][p] * d3;
    }
    red[0][t] = p0; red[1][t] = p1; red[2][t] = p2; red[3][t] = p3;
    __syncthreads();
    for (int s = 128; s > 0; s >>= 1) {
        if (t < s) {
            red[0][t] += red[0][t + s];
            red[1][t] += red[1][t + s];
            red[2][t] += red[2][t + s];
            red[3][t] += red[3][t + s];
        }
        __syncthreads();
    }
    if (t < 4) kinv[n0 + t] = 1.0f / sqrtf(red[t][0]);
}

// ---------------- kernel 5: main pair GEMM — 8 waves (512 thr), bf16 Tb staging ----------
__global__ __launch_bounds__(512, 6) void k4_kernel(const uint8_t* X8, const unsigned short* Tb,
                                                    const unsigned short* wswz, const float* kinv,
                                                    const float* Ainp, float* out) {
    __shared__ unsigned short Sh[32 * 520];
    __shared__ unsigned short Ts1h[4 * TBSTRIDE];
    __shared__ unsigned short Ts2h[8 * TBSTRIDE];
    __shared__ unsigned short A21[4 * 512];
    __shared__ uint8_t Xs2[8 * 512];
    __shared__ float Kacc[8][32];

    int t = threadIdx.x;
    int i0 = blockIdx.x * 4;
    int j0 = blockIdx.y * 8;

    for (int e = t; e < 4 * 512; e += 512)
        A21[e] = (unsigned short)(21 * X8[(size_t)(i0 + (e >> 9)) * 512 + (e & 511)]);
    {
        const uint32_t* s2 = (const uint32_t*)(X8 + (size_t)(256 + j0) * 512);
        uint32_t* d2 = (uint32_t*)Xs2;
        for (int e = t; e < 1024; e += 512) d2[e] = s2[e];
    }
    {
        // Tb rows are already 0.5*T in bf16 — straight u32 copies (448 u16 = 224 u32 per row)
        uint32_t* d1 = (uint32_t*)Ts1h;
        for (int e = t; e < 4 * 224; e += 512) {
            int r = e / 224, w = e - r * 224;
            d1[e] = ((const uint32_t*)(Tb + (size_t)(i0 + r) * TBSTRIDE))[w];
        }
        uint32_t* d2 = (uint32_t*)Ts2h;
        for (int e = t; e < 8 * 224; e += 512) {
            int r = e / 224, w = e - r * 224;
            d2[e] = ((const uint32_t*)(Tb + (size_t)(256 + j0 + r) * TBSTRIDE))[w];
        }
    }
    __syncthreads();

    // build S tile: 4 elems per thread-iter, packed u64 write
    for (int e4 = t; e4 < 32 * 128; e4 += 512) {
        int pr = e4 >> 7, p = (e4 & 127) * 4;
        int ti = pr >> 3, tj = pr & 7;
        uint64_t a4 = *(const uint64_t*)&A21[ti * 512 + p];   // 4 u16 (a*21)
        uint32_t b4 = *(const uint32_t*)&Xs2[tj * 512 + p];   // 4 u8
        const unsigned short* T1 = &Ts1h[ti * TBSTRIDE];
        const unsigned short* T2 = &Ts2h[tj * TBSTRIDE];
        uint64_t outw = 0;
#pragma unroll
        for (int u = 0; u < 4; ++u) {
            int idx = (int)((a4 >> (16 * u)) & 0xFFFFu) + (int)((b4 >> (8 * u)) & 0xFFu);
            float v = b2f(T1[idx]) + b2f(T2[idx]);
            outw |= (uint64_t)f2b(v) << (16 * u);
        }
        *(uint64_t*)&Sh[pr * 520 + p] = outw;
    }
    __syncthreads();

    int wid = t >> 6, lane = t & 63;
    int lr = lane & 31, hf = lane >> 5;
    int n_base = wid * 64;

    const unsigned short* Sa = &Sh[lr * 520 + hf * 8];
    const unsigned short* Bz0 = wswz + (size_t)((wid * 2 + 0) * 32) * 512 + lane * 8;
    const unsigned short* Bz1 = wswz + (size_t)((wid * 2 + 1) * 32) * 512 + lane * 8;

    f32x16 acc0, acc1;
#pragma unroll
    for (int j = 0; j < 16; ++j) { acc0[j] = 0.f; acc1[j] = 0.f; }

#pragma unroll 2
    for (int kt = 0; kt < 32; ++kt) {
        bf16x8 av = *(const bf16x8*)(Sa + kt * 16);
        bf16x8 bv0 = *(const bf16x8*)(Bz0 + kt * 512);
        bf16x8 bv1 = *(const bf16x8*)(Bz1 + kt * 512);
        acc0 = __builtin_amdgcn_mfma_f32_32x32x16_bf16(av, bv0, acc0, 0, 0, 0);
        acc1 = __builtin_amdgcn_mfma_f32_32x32x16_bf16(av, bv1, acc1, 0, 0, 0);
    }

    float prow[16];
#pragma unroll
    for (int r = 0; r < 16; ++r) {
        int row = (r & 3) + 8 * (r >> 2) + 4 * hf;
        float v = acc0[r] * b2f(Sh[row * 520 + (n_base + lr)]);
        v      += acc1[r] * b2f(Sh[row * 520 + (n_base + 32 + lr)]);
        prow[r] = v;
    }
#pragma unroll
    for (int r = 0; r < 16; ++r) {
        float v = prow[r];
        v += __shfl_xor(v, 1);
        v += __shfl_xor(v, 2);
        v += __shfl_xor(v, 4);
        v += __shfl_xor(v, 8);
        v += __shfl_xor(v, 16);
        if (lr == 0) {
            int row = (r & 3) + 8 * (r >> 2) + 4 * hf;
            Kacc[wid][row] = v;
        }
    }
    __syncthreads();

    if (t < 32) {
        float K = Kacc[0][t] + Kacc[1][t] + Kacc[2][t] + Kacc[3][t]
                + Kacc[4][t] + Kacc[5][t] + Kacc[6][t] + Kacc[7][t];
        int ti = t >> 3, tj = t & 7;
        int i = i0 + ti, j = j0 + tj;
        float a0 = Ainp[0];
        out[i * 256 + j] = a0 * a0 * K * kinv[i] * kinv[256 + j];
    }
}

// ---------------- launcher ----------------
extern "C" void kernel_launch(void* const* d_in, const int* in_sizes, int n_in,
                              void* d_out, int out_size, void* d_ws, size_t ws_size,
                              hipStream_t stream) {
    const int*   X1 = (const int*)d_in[0];
    const int*   X2 = (const int*)d_in[1];
    const float* W  = (const float*)d_in[2];
    const float* b  = (const float*)d_in[3];
    const float* wp = (const float*)d_in[4];
    const float* a  = (const float*)d_in[5];
    float* out = (float*)d_out;

    char* ws = (char*)d_ws;
    float*          E     = (float*)(ws + 0);                  //  5,505,024
    unsigned short* Tb    = (unsigned short*)(ws + 5505024);   //    458,752
    float*          Tdiag = (float*)(ws + 5963776);            //     49,152
    float*          w32   = (float*)(ws + 6012928);            //  1,048,576
    unsigned short* wswz  = (unsigned short*)(ws + 7061504);   //    524,288
    float*          kinv  = (float*)(ws + 7585792);            //      2,048
    uint8_t*        X8    = (uint8_t*)(ws + 7587840);          //    262,144
    unsigned short* Abz   = (unsigned short*)(ws + 7849984);   // 11,010,048
    unsigned short* Wbz   = (unsigned short*)(ws + 18860032);  // 57,802,752 (end 76,662,784)

    prep_kernel<<<PB_TOTAL, 256, 0, stream>>>(X1, X2, W, b, wp, X8, w32, wswz, E, Wbz, Abz);
    e_mfma_v3<<<1008, 256, 0, stream>>>(Abz, Wbz, E);
    t_kernel<<<512, 256, 0, stream>>>(E, Tb, Tdiag);
    k_kernel<<<128, 256, 0, stream>>>(X8, Tdiag, w32, kinv);
    k4_kernel<<<dim3(64, 32), 512, 0, stream>>>(X8, Tb, wswz, kinv, a, out);
}

// Round 4
// 355.254 us; speedup vs baseline: 1.0774x; 1.0594x over previous
//
#include <hip/hip_runtime.h>
#include <cstdint>
#include <cstddef>

// ---------------- types / helpers ----------------
typedef __attribute__((ext_vector_type(8))) __bf16 bf16x8;
typedef __attribute__((ext_vector_type(4))) float f32x4;
typedef __attribute__((ext_vector_type(16))) float f32x16;

__device__ __forceinline__ unsigned short f2b(float x) {
    uint32_t u = __float_as_uint(x);
    u += 0x7FFFu + ((u >> 16) & 1u);   // RNE
    return (unsigned short)(u >> 16);
}
__device__ __forceinline__ float b2f(unsigned short h) {
    return __uint_as_float(((uint32_t)h) << 16);
}

#define L_SEQ 512
#define N_AA 21
#define DDIM 128
#define NCOL 2688        // 21*128
#define NSEQ 512         // 256 + 256
#define TBSTRIDE 448     // Tb row stride (u16), 441 used
#define KTOT 10752       // 512*21
#define KWORDS_TOT 336   // 10752/32
#define KWORDS 28        // words per k-chunk (896/32)
#define ZCH 12           // k-chunks
#define KBTOT 672        // 10752/16 k-subtiles
#define KBCH 56          // 672/12 k-subtiles per chunk

// block-range sizes inside prep_kernel
#define PB_WBZ   14112   // 84*672/4 fragments
#define PB_EINIT 5376
#define PB_REPACK 1024
#define PB_WBUILD 1024
#define PB_ABITS 672
#define PB_TOTAL (PB_WBZ + PB_EINIT + PB_REPACK + PB_WBUILD + PB_ABITS)

// ---------------- kernel 1: fused prologue ----------------
// Independent sub-jobs, dispatched by blockIdx range:
//   [0, 14112)     : W fp32 -> Wbz bf16 fragment-swizzled
//   [+5376)        : E init with bias
//   [+1024)        : X1/X2 int32 -> X8 u8
//   [+1024)        : w32 = sigmoid(wm), wswz = bf16 MFMA-frag order
//   [+672)         : one-hot bitmask Abits (reads X1/X2 directly)
__global__ __launch_bounds__(256) void prep_kernel(const int* X1, const int* X2,
                                                   const float* W, const float* bvec, const float* wp,
                                                   uint8_t* X8, uint32_t* Abits,
                                                   float* w32, unsigned short* wswz,
                                                   float* E, unsigned short* Wbz) {
    int bid = blockIdx.x;
    int t = threadIdx.x;
    if (bid < PB_WBZ) {
        // Wbz fragment (cb,kb): lane (hf,lr) holds W[kb*16+hf*8+j][cb*32+lr], j=0..7
        int f = bid * 4 + (t >> 6);
        int lane = t & 63, lr = lane & 31, hf = lane >> 5;
        int cb = f / KBTOT, kb = f - cb * KBTOT;
        const float* src = W + (size_t)(kb * 16 + hf * 8) * NCOL + cb * 32 + lr;
        union { uint4 q; unsigned short s[8]; } o;
#pragma unroll
        for (int j = 0; j < 8; ++j) o.s[j] = f2b(src[(size_t)j * NCOL]);
        *(uint4*)&Wbz[(size_t)f * 512 + lane * 8] = o.q;
        return;
    }
    bid -= PB_WBZ;
    if (bid < PB_EINIT) {
        int e = bid * 256 + t;             // 1,376,256
        E[e] = bvec[e % NCOL];
        return;
    }
    bid -= PB_EINIT;
    if (bid < PB_REPACK) {
        int e = bid * 256 + t;             // 262,144
        if (e < 131072) X8[e] = (uint8_t)X1[e];
        else            X8[e] = (uint8_t)X2[e - 131072];
        return;
    }
    bid -= PB_REPACK;
    if (bid < PB_WBUILD) {
        int e = bid * 256 + t;             // 262,144 = 512*512
        int p = e >> 9, q = e & 511;
        float x = 0.0f;
        if (p > q)      x = wp[p * (p - 1) / 2 + q];
        else if (p < q) x = wp[q * (q - 1) / 2 + p];
        float s = 1.0f / (1.0f + expf(-x));
        w32[e] = s;
        int nb = p >> 5, lr = p & 31;
        int kb = q >> 4, hf = (q >> 3) & 1, j = q & 7;
        wswz[(size_t)((nb * 32 + kb) * 512) + (hf * 32 + lr) * 8 + j] = f2b(s);
        return;
    }
    bid -= PB_WBUILD;
    {
        int e = bid * 256 + t;             // 172,032 = 512*336
        if (e >= NSEQ * KWORDS_TOT) return;
        int seq = e / KWORDS_TOT, w = e - seq * KWORDS_TOT;
        int k0 = w * 32;
        int l_lo = k0 / N_AA;
        int l_hi = (k0 + 31) / N_AA;
        if (l_hi > L_SEQ - 1) l_hi = L_SEQ - 1;
        uint32_t bits = 0;
        for (int l = l_lo; l <= l_hi; ++l) {
            int aa = (seq < 256) ? X1[(size_t)seq * L_SEQ + l]
                                 : X2[(size_t)(seq - 256) * L_SEQ + l];
            int pos = l * N_AA + aa - k0;
            if (pos >= 0 && pos < 32) bits |= (1u << pos);
        }
        Abits[e] = bits;
    }
}

// ---------------- kernel 2: E += A @ W — barrier-free, A built from bitmask ----------
// 1008 blocks (21 c x 4 m x 12 k), XCD-swizzled, 4 waves. Block stages its 128-row Abits
// slice in LDS once (no further barriers). Each wave owns ONE c-fragment (128m x 32c):
// per K-subtile it builds 4 A-frags in VALU from the bitmask and keeps a depth-4 static
// register ring for B (loads issued 4 iterations ahead; waves fully decoupled).
__global__ __launch_bounds__(256, 4) void e_mfma_v4(const uint32_t* Abits, const unsigned short* Wbz, float* E) {
    __shared__ uint32_t Ab[128 * 29];

    int lin = blockIdx.x;
    int s_ = ((lin & 7) * 126) + (lin >> 3);   // bijective XCD swizzle (1008 % 8 == 0)
    int cx = s_ % 21;
    int rem = s_ / 21;
    int my = rem & 3;
    int kz = rem >> 2;

    int t = threadIdx.x, wid = t >> 6, lane = t & 63;
    int lr = lane & 31, hf = lane >> 5, hf8 = hf * 8;
    int m0 = my * 128;
    int w0 = kz * KWORDS;
    int kb0 = kz * KBCH;

    for (int idx = t; idx < 128 * KWORDS; idx += 256) {
        int r = idx / KWORDS, w = idx - r * KWORDS;
        Ab[r * 29 + w] = Abits[(size_t)(m0 + r) * KWORDS_TOT + w0 + w];
    }
    __syncthreads();   // the only barrier in this kernel

    int cb = cx * 4 + wid;
    const unsigned short* Bp = Wbz + ((size_t)(cb * KBTOT + kb0)) * 512 + lane * 8;

    f32x16 acc0, acc1, acc2, acc3;
#pragma unroll
    for (int r = 0; r < 16; ++r) { acc0[r] = 0.f; acc1[r] = 0.f; acc2[r] = 0.f; acc3[r] = 0.f; }

    // depth-4 B register ring (statically indexed; loads 4 iters ahead)
    bf16x8 br0 = *(const bf16x8*)(Bp + 0 * 512);
    bf16x8 br1 = *(const bf16x8*)(Bp + 1 * 512);
    bf16x8 br2 = *(const bf16x8*)(Bp + 2 * 512);
    bf16x8 br3 = *(const bf16x8*)(Bp + 3 * 512);

#define AFRAG(S, WORD, SH) ({ \
        uint32_t bits_ = Ab[((S) * 32 + lr) * 29 + (WORD)]; \
        uint32_t bb_ = (bits_ >> (SH)) & 0xFFu; \
        union { bf16x8 v; uint32_t u[4]; } af_; \
        af_.u[0] = ((bb_ & 1u)   ? 0x3F80u : 0u) | ((bb_ & 2u)   ? 0x3F800000u : 0u); \
        af_.u[1] = ((bb_ & 4u)   ? 0x3F80u : 0u) | ((bb_ & 8u)   ? 0x3F800000u : 0u); \
        af_.u[2] = ((bb_ & 16u)  ? 0x3F80u : 0u) | ((bb_ & 32u)  ? 0x3F800000u : 0u); \
        af_.u[3] = ((bb_ & 64u)  ? 0x3F80u : 0u) | ((bb_ & 128u) ? 0x3F800000u : 0u); \
        af_.v; })

#define STEP(BV, KB) do { \
        int word_ = (KB) >> 1; \
        int sh_ = ((KB) & 1) * 16 + hf8; \
        acc0 = __builtin_amdgcn_mfma_f32_32x32x16_bf16(AFRAG(0, word_, sh_), BV, acc0, 0, 0, 0); \
        acc1 = __builtin_amdgcn_mfma_f32_32x32x16_bf16(AFRAG(1, word_, sh_), BV, acc1, 0, 0, 0); \
        acc2 = __builtin_amdgcn_mfma_f32_32x32x16_bf16(AFRAG(2, word_, sh_), BV, acc2, 0, 0, 0); \
        acc3 = __builtin_amdgcn_mfma_f32_32x32x16_bf16(AFRAG(3, word_, sh_), BV, acc3, 0, 0, 0); \
    } while (0)

#pragma unroll 1
    for (int kb = 0; kb < 48; kb += 4) {
        STEP(br0, kb + 0); br0 = *(const bf16x8*)(Bp + (size_t)(kb + 4) * 512);
        STEP(br1, kb + 1); br1 = *(const bf16x8*)(Bp + (size_t)(kb + 5) * 512);
        STEP(br2, kb + 2); br2 = *(const bf16x8*)(Bp + (size_t)(kb + 6) * 512);
        STEP(br3, kb + 3); br3 = *(const bf16x8*)(Bp + (size_t)(kb + 7) * 512);
    }
    STEP(br0, 48); br0 = *(const bf16x8*)(Bp + 52 * 512);
    STEP(br1, 49); br1 = *(const bf16x8*)(Bp + 53 * 512);
    STEP(br2, 50); br2 = *(const bf16x8*)(Bp + 54 * 512);
    STEP(br3, 51); br3 = *(const bf16x8*)(Bp + 55 * 512);
    STEP(br0, 52); STEP(br1, 53); STEP(br2, 54); STEP(br3, 55);

#undef STEP
#undef AFRAG

#pragma unroll
    for (int r = 0; r < 16; ++r) {
        int row = (r & 3) + 8 * (r >> 2) + 4 * hf;
        float* b0p = E + (size_t)(m0 + row) * NCOL + cb * 32 + lr;
        atomicAdd(b0p, acc0[r]);
        atomicAdd(b0p + 32 * NCOL, acc1[r]);
        atomicAdd(b0p + 64 * NCOL, acc2[r]);
        atomicAdd(b0p + 96 * NCOL, acc3[r]);
    }
}

// ---------------- kernel 3: T[n] = E[n] @ E[n]^T (21x21) -> bf16 Tb (0.5x) + fp32 diag ----
__global__ __launch_bounds__(256) void t_kernel(const float* E, unsigned short* Tb, float* Tdiag) {
    __shared__ float4 Es4[21 * 33];
    int t = threadIdx.x, n = blockIdx.x;
    for (int e = t; e < 21 * 32; e += 256) {
        int r = e >> 5, d = e & 31;
        Es4[r * 33 + d] = *(const float4*)(E + (size_t)n * NCOL + r * 128 + d * 4);
    }
    __syncthreads();
    for (int e = t; e < 441; e += 256) {
        int r = e / 21, c = e - r * 21;
        const float4* ar = &Es4[r * 33];
        const float4* br = &Es4[c * 33];
        float s = 0.f;
#pragma unroll 8
        for (int d = 0; d < 32; ++d) {
            float4 a = ar[d], b = br[d];
            s += a.x * b.x + a.y * b.y + a.z * b.z + a.w * b.w;
        }
        Tb[(size_t)n * TBSTRIDE + e] = f2b(0.5f * s);
        if (r == c) Tdiag[n * 24 + r] = s;
    }
}

// ---------------- kernel 4: kinv — coalesced wave-per-row bilinear form ----------------
// 128 blocks x 512 thr (8 waves), 4 seqs/block. Lane owns q-slice [lane*8, lane*8+8).
// Per p-row: lanes read w32[p] coalesced (2KB/wave-inst), r_q += d_p * w_pq; finally
// kk = sum_q r_q d_q via one dot + wave shuffle reduce. Same fp32 math as before.
__global__ __launch_bounds__(512) void k_kernel(const uint8_t* X8, const float* Tdiag, const float* w32, float* kinv) {
    __shared__ __align__(16) float dvec[4][512];
    __shared__ float Td[4][21];
    __shared__ float wred[4][8];
    int t = threadIdx.x, n0 = blockIdx.x * 4;
    if (t < 84) Td[t / 21][t % 21] = Tdiag[(size_t)(n0 + t / 21) * 24 + (t % 21)];
    __syncthreads();
    for (int e = t; e < 2048; e += 512) {
        int nn = e >> 9, l = e & 511;
        dvec[nn][l] = Td[nn][X8[(size_t)(n0 + nn) * 512 + l]];
    }
    __syncthreads();
    int wid = t >> 6, lane = t & 63;
    int q0 = lane * 8;

    float4 dA0 = *(const float4*)&dvec[0][q0], dA1 = *(const float4*)&dvec[0][q0 + 4];
    float4 dB0 = *(const float4*)&dvec[1][q0], dB1 = *(const float4*)&dvec[1][q0 + 4];
    float4 dC0 = *(const float4*)&dvec[2][q0], dC1 = *(const float4*)&dvec[2][q0 + 4];
    float4 dD0 = *(const float4*)&dvec[3][q0], dD1 = *(const float4*)&dvec[3][q0 + 4];

    float4 rA0 = {0,0,0,0}, rA1 = {0,0,0,0}, rB0 = {0,0,0,0}, rB1 = {0,0,0,0};
    float4 rC0 = {0,0,0,0}, rC1 = {0,0,0,0}, rD0 = {0,0,0,0}, rD1 = {0,0,0,0};

#define FMA4(R, W, S) do { (R).x += (W).x * (S); (R).y += (W).y * (S); (R).z += (W).z * (S); (R).w += (W).w * (S); } while (0)
    for (int p = wid; p < 512; p += 8) {
        const float4* wr = (const float4*)(w32 + (size_t)p * 512 + q0);
        float4 w0v = wr[0], w1v = wr[1];
        float a = dvec[0][p], b = dvec[1][p], c = dvec[2][p], d = dvec[3][p];
        FMA4(rA0, w0v, a); FMA4(rA1, w1v, a);
        FMA4(rB0, w0v, b); FMA4(rB1, w1v, b);
        FMA4(rC0, w0v, c); FMA4(rC1, w1v, c);
        FMA4(rD0, w0v, d); FMA4(rD1, w1v, d);
    }
#undef FMA4

#define DOT8(R0, R1, D0, D1) ((R0).x*(D0).x + (R0).y*(D0).y + (R0).z*(D0).z + (R0).w*(D0).w + \
                              (R1).x*(D1).x + (R1).y*(D1).y + (R1).z*(D1).z + (R1).w*(D1).w)
    float s0 = DOT8(rA0, rA1, dA0, dA1);
    float s1 = DOT8(rB0, rB1, dB0, dB1);
    float s2 = DOT8(rC0, rC1, dC0, dC1);
    float s3 = DOT8(rD0, rD1, dD0, dD1);
#undef DOT8

#pragma unroll
    for (int off = 1; off < 64; off <<= 1) {
        s0 += __shfl_xor(s0, off);
        s1 += __shfl_xor(s1, off);
        s2 += __shfl_xor(s2, off);
        s3 += __shfl_xor(s3, off);
    }
    if (lane == 0) { wred[0][wid] = s0; wred[1][wid] = s1; wred[2][wid] = s2; wred[3][wid] = s3; }
    __syncthreads();
    if (t < 4) {
        float kk = 0.f;
#pragma unroll
        for (int w = 0; w < 8; ++w) kk += wred[t][w];
        kinv[n0 + t] = 1.0f / sqrtf(kk);
    }
}

// ---------------- kernel 5: main pair GEMM — 8 waves (512 thr), bf16 Tb staging ----------
__global__ __launch_bounds__(512, 6) void k4_kernel(const uint8_t* X8, const unsigned short* Tb,
                                                    const unsigned short* wswz, const float* kinv,
                                                    const float* Ainp, float* out) {
    __shared__ unsigned short Sh[32 * 520];
    __shared__ unsigned short Ts1h[4 * TBSTRIDE];
    __shared__ unsigned short Ts2h[8 * TBSTRIDE];
    __shared__ unsigned short A21[4 * 512];
    __shared__ uint8_t Xs2[8 * 512];
    __shared__ float Kacc[8][32];

    int t = threadIdx.x;
    int i0 = blockIdx.x * 4;
    int j0 = blockIdx.y * 8;

    for (int e = t; e < 4 * 512; e += 512)
        A21[e] = (unsigned short)(21 * X8[(size_t)(i0 + (e >> 9)) * 512 + (e & 511)]);
    {
        const uint32_t* s2 = (const uint32_t*)(X8 + (size_t)(256 + j0) * 512);
        uint32_t* d2 = (uint32_t*)Xs2;
        for (int e = t; e < 1024; e += 512) d2[e] = s2[e];
    }
    {
        // Tb rows are already 0.5*T in bf16 — straight u32 copies (448 u16 = 224 u32 per row)
        uint32_t* d1 = (uint32_t*)Ts1h;
        for (int e = t; e < 4 * 224; e += 512) {
            int r = e / 224, w = e - r * 224;
            d1[e] = ((const uint32_t*)(Tb + (size_t)(i0 + r) * TBSTRIDE))[w];
        }
        uint32_t* d2 = (uint32_t*)Ts2h;
        for (int e = t; e < 8 * 224; e += 512) {
            int r = e / 224, w = e - r * 224;
            d2[e] = ((const uint32_t*)(Tb + (size_t)(256 + j0 + r) * TBSTRIDE))[w];
        }
    }
    __syncthreads();

    // build S tile: 4 elems per thread-iter, packed u64 write
    for (int e4 = t; e4 < 32 * 128; e4 += 512) {
        int pr = e4 >> 7, p = (e4 & 127) * 4;
        int ti = pr >> 3, tj = pr & 7;
        uint64_t a4 = *(const uint64_t*)&A21[ti * 512 + p];   // 4 u16 (a*21)
        uint32_t b4 = *(const uint32_t*)&Xs2[tj * 512 + p];   // 4 u8
        const unsigned short* T1 = &Ts1h[ti * TBSTRIDE];
        const unsigned short* T2 = &Ts2h[tj * TBSTRIDE];
        uint64_t outw = 0;
#pragma unroll
        for (int u = 0; u < 4; ++u) {
            int idx = (int)((a4 >> (16 * u)) & 0xFFFFu) + (int)((b4 >> (8 * u)) & 0xFFu);
            float v = b2f(T1[idx]) + b2f(T2[idx]);
            outw |= (uint64_t)f2b(v) << (16 * u);
        }
        *(uint64_t*)&Sh[pr * 520 + p] = outw;
    }
    __syncthreads();

    int wid = t >> 6, lane = t & 63;
    int lr = lane & 31, hf = lane >> 5;
    int n_base = wid * 64;

    const unsigned short* Sa = &Sh[lr * 520 + hf * 8];
    const unsigned short* Bz0 = wswz + (size_t)((wid * 2 + 0) * 32) * 512 + lane * 8;
    const unsigned short* Bz1 = wswz + (size_t)((wid * 2 + 1) * 32) * 512 + lane * 8;

    f32x16 acc0, acc1;
#pragma unroll
    for (int j = 0; j < 16; ++j) { acc0[j] = 0.f; acc1[j] = 0.f; }

#pragma unroll 2
    for (int kt = 0; kt < 32; ++kt) {
        bf16x8 av = *(const bf16x8*)(Sa + kt * 16);
        bf16x8 bv0 = *(const bf16x8*)(Bz0 + kt * 512);
        bf16x8 bv1 = *(const bf16x8*)(Bz1 + kt * 512);
        acc0 = __builtin_amdgcn_mfma_f32_32x32x16_bf16(av, bv0, acc0, 0, 0, 0);
        acc1 = __builtin_amdgcn_mfma_f32_32x32x16_bf16(av, bv1, acc1, 0, 0, 0);
    }

    float prow[16];
#pragma unroll
    for (int r = 0; r < 16; ++r) {
        int row = (r & 3) + 8 * (r >> 2) + 4 * hf;
        float v = acc0[r] * b2f(Sh[row * 520 + (n_base + lr)]);
        v      += acc1[r] * b2f(Sh[row * 520 + (n_base + 32 + lr)]);
        prow[r] = v;
    }
#pragma unroll
    for (int r = 0; r < 16; ++r) {
        float v = prow[r];
        v += __shfl_xor(v, 1);
        v += __shfl_xor(v, 2);
        v += __shfl_xor(v, 4);
        v += __shfl_xor(v, 8);
        v += __shfl_xor(v, 16);
        if (lr == 0) {
            int row = (r & 3) + 8 * (r >> 2) + 4 * hf;
            Kacc[wid][row] = v;
        }
    }
    __syncthreads();

    if (t < 32) {
        float K = Kacc[0][t] + Kacc[1][t] + Kacc[2][t] + Kacc[3][t]
                + Kacc[4][t] + Kacc[5][t] + Kacc[6][t] + Kacc[7][t];
        int ti = t >> 3, tj = t & 7;
        int i = i0 + ti, j = j0 + tj;
        float a0 = Ainp[0];
        out[i * 256 + j] = a0 * a0 * K * kinv[i] * kinv[256 + j];
    }
}

// ---------------- launcher ----------------
extern "C" void kernel_launch(void* const* d_in, const int* in_sizes, int n_in,
                              void* d_out, int out_size, void* d_ws, size_t ws_size,
                              hipStream_t stream) {
    const int*   X1 = (const int*)d_in[0];
    const int*   X2 = (const int*)d_in[1];
    const float* W  = (const float*)d_in[2];
    const float* b  = (const float*)d_in[3];
    const float* wp = (const float*)d_in[4];
    const float* a  = (const float*)d_in[5];
    float* out = (float*)d_out;

    char* ws = (char*)d_ws;
    float*          E     = (float*)(ws + 0);                  //  5,505,024
    unsigned short* Tb    = (unsigned short*)(ws + 5505024);   //    458,752
    float*          Tdiag = (float*)(ws + 5963776);            //     49,152
    float*          w32   = (float*)(ws + 6012928);            //  1,048,576
    unsigned short* wswz  = (unsigned short*)(ws + 7061504);   //    524,288
    float*          kinv  = (float*)(ws + 7585792);            //      2,048
    uint8_t*        X8    = (uint8_t*)(ws + 7587840);          //    262,144
    uint32_t*       Abits = (uint32_t*)(ws + 7849984);         //    688,128
    unsigned short* Wbz   = (unsigned short*)(ws + 8538112);   // 57,802,752 (end 66,340,864)

    prep_kernel<<<PB_TOTAL, 256, 0, stream>>>(X1, X2, W, b, wp, X8, Abits, w32, wswz, E, Wbz);
    e_mfma_v4<<<1008, 256, 0, stream>>>(Abits, Wbz, E);
    t_kernel<<<512, 256, 0, stream>>>(E, Tb, Tdiag);
    k_kernel<<<128, 512, 0, stream>>>(X8, Tdiag, w32, kinv);
    k4_kernel<<<dim3(64, 32), 512, 0, stream>>>(X8, Tb, wswz, kinv, a, out);
}

// Round 5
// 327.385 us; speedup vs baseline: 1.1691x; 1.0851x over previous
//
#include <hip/hip_runtime.h>
#include <cstdint>
#include <cstddef>

// ---------------- types / helpers ----------------
typedef __attribute__((ext_vector_type(8))) __bf16 bf16x8;
typedef __attribute__((ext_vector_type(4))) float f32x4;
typedef __attribute__((ext_vector_type(16))) float f32x16;

__device__ __forceinline__ unsigned short f2b(float x) {
    uint32_t u = __float_as_uint(x);
    u += 0x7FFFu + ((u >> 16) & 1u);   // RNE
    return (unsigned short)(u >> 16);
}
__device__ __forceinline__ float b2f(unsigned short h) {
    return __uint_as_float(((uint32_t)h) << 16);
}

// async global->LDS, 16B per lane. LDS dest is wave-uniform base (+lane*16 by HW).
__device__ __forceinline__ void gl16(const unsigned short* g, unsigned short* l) {
    __builtin_amdgcn_global_load_lds((const __attribute__((address_space(1))) uint32_t*)g,
                                     (__attribute__((address_space(3))) uint32_t*)l, 16, 0, 0);
}

#define L_SEQ 512
#define N_AA 21
#define DDIM 128
#define NCOL 2688        // 21*128
#define NSEQ 512         // 256 + 256
#define TBSTRIDE 448     // Tb row stride (u16), 441 used
#define KTOT 10752       // 512*21
#define ZCH 8            // k-chunks (partial-slab count)
#define KBTOT 672        // 10752/16 k-subtiles
#define KBCH 84          // 672/8 k-subtiles per chunk

// block-range sizes inside prep_kernel
#define PB_WBZ   14112   // 84*672/4 fragments
#define PB_REPACK 1024
#define PB_WBUILD 1024
#define PB_ABZ   2688    // 16*672/4 fragments
#define PB_TOTAL (PB_WBZ + PB_REPACK + PB_WBUILD + PB_ABZ)

// ---------------- kernel 1: fused prologue ----------------
// Independent sub-jobs, dispatched by blockIdx range:
//   [0, 14112)     : W fp32 -> Wbz bf16 fragment-swizzled
//   [+1024)        : X1/X2 int32 -> X8 u8
//   [+1024)        : w32 = sigmoid(wm), wswz = bf16 MFMA-frag order
//   [+2688)        : one-hot A -> Abz bf16 fragment-swizzled (reads X1/X2)
__global__ __launch_bounds__(256) void prep_kernel(const int* X1, const int* X2,
                                                   const float* W, const float* wp,
                                                   uint8_t* X8,
                                                   float* w32, unsigned short* wswz,
                                                   unsigned short* Wbz, unsigned short* Abz) {
    int bid = blockIdx.x;
    int t = threadIdx.x;
    if (bid < PB_WBZ) {
        // Wbz fragment (cb,kb): lane (hf,lr) holds W[kb*16+hf*8+j][cb*32+lr], j=0..7
        int f = bid * 4 + (t >> 6);
        int lane = t & 63, lr = lane & 31, hf = lane >> 5;
        int cb = f / KBTOT, kb = f - cb * KBTOT;
        const float* src = W + (size_t)(kb * 16 + hf * 8) * NCOL + cb * 32 + lr;
        union { uint4 q; unsigned short s[8]; } o;
#pragma unroll
        for (int j = 0; j < 8; ++j) o.s[j] = f2b(src[(size_t)j * NCOL]);
        *(uint4*)&Wbz[(size_t)f * 512 + lane * 8] = o.q;
        return;
    }
    bid -= PB_WBZ;
    if (bid < PB_REPACK) {
        int e = bid * 256 + t;             // 262,144
        if (e < 131072) X8[e] = (uint8_t)X1[e];
        else            X8[e] = (uint8_t)X2[e - 131072];
        return;
    }
    bid -= PB_REPACK;
    if (bid < PB_WBUILD) {
        int e = bid * 256 + t;             // 262,144 = 512*512
        int p = e >> 9, q = e & 511;
        float x = 0.0f;
        if (p > q)      x = wp[p * (p - 1) / 2 + q];
        else if (p < q) x = wp[q * (q - 1) / 2 + p];
        float s = 1.0f / (1.0f + expf(-x));
        w32[e] = s;
        int nb = p >> 5, lr = p & 31;
        int kb = q >> 4, hf = (q >> 3) & 1, j = q & 7;
        wswz[(size_t)((nb * 32 + kb) * 512) + (hf * 32 + lr) * 8 + j] = f2b(s);
        return;
    }
    bid -= PB_WBUILD;
    {
        // Abz fragment (mb,kb): lane (hf,lr) holds onehot(X[mb*32+lr], k=kb*16+hf*8+j)
        int f = bid * 4 + (t >> 6);        // 0..10751
        int lane = t & 63, lr = lane & 31, hf = lane >> 5;
        int mb = f / KBTOT, kb = f - mb * KBTOT;
        int m = mb * 32 + lr;
        const int* Xrow = (m < 256) ? (X1 + (size_t)m * L_SEQ) : (X2 + (size_t)(m - 256) * L_SEQ);
        int k0 = kb * 16 + hf * 8;
        union { uint4 q; unsigned short s[8]; } o;
#pragma unroll
        for (int j = 0; j < 8; ++j) {
            int k = k0 + j;
            int l = k / N_AA;
            int aa = k - l * N_AA;
            o.s[j] = (Xrow[l] == aa) ? (unsigned short)0x3F80u : (unsigned short)0u;
        }
        *(uint4*)&Abz[(size_t)f * 512 + lane * 8] = o.q;
    }
}

// ---------------- kernel 2: Ep[kz] = A @ W (k-chunk partial) — LDS ring, PLAIN STORES ---
// 672 blocks (21 c x 4 m x 8 k), XCD-swizzled, 4 waves. Per K-step the block stages its
// 8 unique fragments (4 A + 4 B, 8 KB) once via global_load_lds into a 4-deep ring;
// counted vmcnt(6) keeps 3 K-steps of loads in flight across raw s_barriers.
// Epilogue: plain coalesced stores to the kz partial slab (NO atomics — the round-4
// counters showed the 12-way atomicAdd epilogue was ~50 us of HBM-level RMW).
__global__ __launch_bounds__(256, 4) void e_mfma_v5(const unsigned short* Abz, const unsigned short* Wbz, float* Ep) {
    __shared__ unsigned short lds[4 * 8 * 512];   // 4 bufs x 8 frags x 1024 B = 32 KB

    int lin = blockIdx.x;
    int s = ((lin & 7) * 84) + (lin >> 3);    // bijective XCD swizzle (672 % 8 == 0)
    int cx = s % 21;
    int rem = s / 21;                          // 0..31
    int my = rem & 3;
    int kz = rem >> 2;                         // 0..7

    int t = threadIdx.x, wid = t >> 6, lane = t & 63;
    int lr = lane & 31, hf = lane >> 5;
    int kb0 = kz * KBCH;

    // per-wave staging sources (global, per-lane addr) and LDS dests (wave-uniform)
    const unsigned short* Aw = Abz + ((size_t)((my * 4 + wid) * KBTOT + kb0)) * 512 + lane * 8;
    const unsigned short* Bw = Wbz + ((size_t)((cx * 4 + wid) * KBTOT + kb0)) * 512 + lane * 8;
    unsigned short* La = &lds[wid * 512];
    unsigned short* Lb = &lds[(4 + wid) * 512];

#define STG(buf_, kb_) do { \
        gl16(Aw + (size_t)(kb_) * 512, La + (buf_) * 4096); \
        gl16(Bw + (size_t)(kb_) * 512, Lb + (buf_) * 4096); \
    } while (0)

    int alo = (wid & 1) * 2;          // A frag slots this wave consumes
    int blo = 4 + (wid >> 1) * 2;     // B frag slots

    f32x16 acc00, acc01, acc10, acc11;
#pragma unroll
    for (int r = 0; r < 16; ++r) { acc00[r] = 0.f; acc01[r] = 0.f; acc10[r] = 0.f; acc11[r] = 0.f; }

#define COMPUTE(kb_) do { \
        const unsigned short* base = &lds[((kb_) & 3) * 4096]; \
        bf16x8 a0 = *(const bf16x8*)(base + (alo + 0) * 512 + lane * 8); \
        bf16x8 a1 = *(const bf16x8*)(base + (alo + 1) * 512 + lane * 8); \
        bf16x8 b0 = *(const bf16x8*)(base + (blo + 0) * 512 + lane * 8); \
        bf16x8 b1 = *(const bf16x8*)(base + (blo + 1) * 512 + lane * 8); \
        acc00 = __builtin_amdgcn_mfma_f32_32x32x16_bf16(a0, b0, acc00, 0, 0, 0); \
        acc01 = __builtin_amdgcn_mfma_f32_32x32x16_bf16(a0, b1, acc01, 0, 0, 0); \
        acc10 = __builtin_amdgcn_mfma_f32_32x32x16_bf16(a1, b0, acc10, 0, 0, 0); \
        acc11 = __builtin_amdgcn_mfma_f32_32x32x16_bf16(a1, b1, acc11, 0, 0, 0); \
    } while (0)

    // prologue: stage kb=0,1,2 (6 loads/wave outstanding)
    STG(0, 0); STG(1, 1); STG(2, 2);

#pragma unroll 1
    for (int kb = 0; kb < KBCH - 3; ++kb) {
        STG((kb + 3) & 3, kb + 3);                      // overwrite buffer read at kb-1 (fenced below)
        asm volatile("s_waitcnt vmcnt(6)" ::: "memory"); // own kb loads landed; 3 steps stay in flight
        __builtin_amdgcn_s_barrier();                    // all waves' kb loads landed
        __builtin_amdgcn_sched_barrier(0);
        COMPUTE(kb);
        __builtin_amdgcn_sched_barrier(0);
        __builtin_amdgcn_s_barrier();                    // all waves done reading buf[kb&3] before restage
    }
    // tail: kb = KBCH-3 .. KBCH-1 (no more staging)
    asm volatile("s_waitcnt vmcnt(4)" ::: "memory");
    __builtin_amdgcn_s_barrier();
    __builtin_amdgcn_sched_barrier(0);
    COMPUTE(KBCH - 3);
    asm volatile("s_waitcnt vmcnt(2)" ::: "memory");
    __builtin_amdgcn_s_barrier();
    __builtin_amdgcn_sched_barrier(0);
    COMPUTE(KBCH - 2);
    asm volatile("s_waitcnt vmcnt(0)" ::: "memory");
    __builtin_amdgcn_s_barrier();
    __builtin_amdgcn_sched_barrier(0);
    COMPUTE(KBCH - 1);

#undef STG
#undef COMPUTE

    int mb0 = my * 4 + (wid & 1) * 2;        // m-fragment index (32-row units)
    int cb0 = cx * 4 + (wid >> 1) * 2;       // c-fragment index (32-col units)
    float* slab = Ep + (size_t)kz * NSEQ * NCOL;
#pragma unroll
    for (int r = 0; r < 16; ++r) {
        int row = (r & 3) + 8 * (r >> 2) + 4 * hf;
        float* base = slab + (size_t)(mb0 * 32 + row) * NCOL + cb0 * 32 + lr;
        base[0] = acc00[r];
        base[32] = acc01[r];
        base[(size_t)32 * NCOL] = acc10[r];
        base[(size_t)32 * NCOL + 32] = acc11[r];
    }
}

// ---------------- kernel 3: T[n] = E[n] @ E[n]^T, E[n] = sum_z Ep[z][n] + bias --------
__global__ __launch_bounds__(256) void t_kernel(const float* Ep, const float* bvec,
                                                unsigned short* Tb, float* Tdiag) {
    __shared__ float4 Es4[21 * 33];
    int t = threadIdx.x, n = blockIdx.x;
    for (int idx = t; idx < 672; idx += 256) {          // 672 float4 = 2688 cols
        const float4* bp = (const float4*)(bvec + idx * 4);
        float4 acc = *bp;
#pragma unroll
        for (int z = 0; z < ZCH; ++z) {
            float4 v = *(const float4*)(Ep + ((size_t)z * NSEQ + n) * NCOL + idx * 4);
            acc.x += v.x; acc.y += v.y; acc.z += v.z; acc.w += v.w;
        }
        int r = idx >> 5, d = idx & 31;
        Es4[r * 33 + d] = acc;
    }
    __syncthreads();
    for (int e = t; e < 441; e += 256) {
        int r = e / 21, c = e - r * 21;
        const float4* ar = &Es4[r * 33];
        const float4* br = &Es4[c * 33];
        float s = 0.f;
#pragma unroll 8
        for (int d = 0; d < 32; ++d) {
            float4 a = ar[d], b = br[d];
            s += a.x * b.x + a.y * b.y + a.z * b.z + a.w * b.w;
        }
        Tb[(size_t)n * TBSTRIDE + e] = f2b(0.5f * s);
        if (r == c) Tdiag[n * 24 + r] = s;
    }
}

// ---------------- kernel 4: kinv — coalesced wave-per-row bilinear form ----------------
__global__ __launch_bounds__(512) void k_kernel(const uint8_t* X8, const float* Tdiag, const float* w32, float* kinv) {
    __shared__ __align__(16) float dvec[4][512];
    __shared__ float Td[4][21];
    __shared__ float wred[4][8];
    int t = threadIdx.x, n0 = blockIdx.x * 4;
    if (t < 84) Td[t / 21][t % 21] = Tdiag[(size_t)(n0 + t / 21) * 24 + (t % 21)];
    __syncthreads();
    for (int e = t; e < 2048; e += 512) {
        int nn = e >> 9, l = e & 511;
        dvec[nn][l] = Td[nn][X8[(size_t)(n0 + nn) * 512 + l]];
    }
    __syncthreads();
    int wid = t >> 6, lane = t & 63;
    int q0 = lane * 8;

    float4 dA0 = *(const float4*)&dvec[0][q0], dA1 = *(const float4*)&dvec[0][q0 + 4];
    float4 dB0 = *(const float4*)&dvec[1][q0], dB1 = *(const float4*)&dvec[1][q0 + 4];
    float4 dC0 = *(const float4*)&dvec[2][q0], dC1 = *(const float4*)&dvec[2][q0 + 4];
    float4 dD0 = *(const float4*)&dvec[3][q0], dD1 = *(const float4*)&dvec[3][q0 + 4];

    float4 rA0 = {0,0,0,0}, rA1 = {0,0,0,0}, rB0 = {0,0,0,0}, rB1 = {0,0,0,0};
    float4 rC0 = {0,0,0,0}, rC1 = {0,0,0,0}, rD0 = {0,0,0,0}, rD1 = {0,0,0,0};

#define FMA4(R, W, S) do { (R).x += (W).x * (S); (R).y += (W).y * (S); (R).z += (W).z * (S); (R).w += (W).w * (S); } while (0)
    for (int p = wid; p < 512; p += 8) {
        const float4* wr = (const float4*)(w32 + (size_t)p * 512 + q0);
        float4 w0v = wr[0], w1v = wr[1];
        float a = dvec[0][p], b = dvec[1][p], c = dvec[2][p], d = dvec[3][p];
        FMA4(rA0, w0v, a); FMA4(rA1, w1v, a);
        FMA4(rB0, w0v, b); FMA4(rB1, w1v, b);
        FMA4(rC0, w0v, c); FMA4(rC1, w1v, c);
        FMA4(rD0, w0v, d); FMA4(rD1, w1v, d);
    }
#undef FMA4

#define DOT8(R0, R1, D0, D1) ((R0).x*(D0).x + (R0).y*(D0).y + (R0).z*(D0).z + (R0).w*(D0).w + \
                              (R1).x*(D1).x + (R1).y*(D1).y + (R1).z*(D1).z + (R1).w*(D1).w)
    float s0 = DOT8(rA0, rA1, dA0, dA1);
    float s1 = DOT8(rB0, rB1, dB0, dB1);
    float s2 = DOT8(rC0, rC1, dC0, dC1);
    float s3 = DOT8(rD0, rD1, dD0, dD1);
#undef DOT8

#pragma unroll
    for (int off = 1; off < 64; off <<= 1) {
        s0 += __shfl_xor(s0, off);
        s1 += __shfl_xor(s1, off);
        s2 += __shfl_xor(s2, off);
        s3 += __shfl_xor(s3, off);
    }
    if (lane == 0) { wred[0][wid] = s0; wred[1][wid] = s1; wred[2][wid] = s2; wred[3][wid] = s3; }
    __syncthreads();
    if (t < 4) {
        float kk = 0.f;
#pragma unroll
        for (int w = 0; w < 8; ++w) kk += wred[t][w];
        kinv[n0 + t] = 1.0f / sqrtf(kk);
    }
}

// ---------------- kernel 5: main pair GEMM — 8 waves (512 thr), bf16 Tb staging ----------
__global__ __launch_bounds__(512, 6) void k4_kernel(const uint8_t* X8, const unsigned short* Tb,
                                                    const unsigned short* wswz, const float* kinv,
                                                    const float* Ainp, float* out) {
    __shared__ unsigned short Sh[32 * 520];
    __shared__ unsigned short Ts1h[4 * TBSTRIDE];
    __shared__ unsigned short Ts2h[8 * TBSTRIDE];
    __shared__ unsigned short A21[4 * 512];
    __shared__ uint8_t Xs2[8 * 512];
    __shared__ float Kacc[8][32];

    int t = threadIdx.x;
    int i0 = blockIdx.x * 4;
    int j0 = blockIdx.y * 8;

    for (int e = t; e < 4 * 512; e += 512)
        A21[e] = (unsigned short)(21 * X8[(size_t)(i0 + (e >> 9)) * 512 + (e & 511)]);
    {
        const uint32_t* s2 = (const uint32_t*)(X8 + (size_t)(256 + j0) * 512);
        uint32_t* d2 = (uint32_t*)Xs2;
        for (int e = t; e < 1024; e += 512) d2[e] = s2[e];
    }
    {
        // Tb rows are already 0.5*T in bf16 — straight u32 copies (448 u16 = 224 u32 per row)
        uint32_t* d1 = (uint32_t*)Ts1h;
        for (int e = t; e < 4 * 224; e += 512) {
            int r = e / 224, w = e - r * 224;
            d1[e] = ((const uint32_t*)(Tb + (size_t)(i0 + r) * TBSTRIDE))[w];
        }
        uint32_t* d2 = (uint32_t*)Ts2h;
        for (int e = t; e < 8 * 224; e += 512) {
            int r = e / 224, w = e - r * 224;
            d2[e] = ((const uint32_t*)(Tb + (size_t)(256 + j0 + r) * TBSTRIDE))[w];
        }
    }
    __syncthreads();

    // build S tile: 4 elems per thread-iter, packed u64 write
    for (int e4 = t; e4 < 32 * 128; e4 += 512) {
        int pr = e4 >> 7, p = (e4 & 127) * 4;
        int ti = pr >> 3, tj = pr & 7;
        uint64_t a4 = *(const uint64_t*)&A21[ti * 512 + p];   // 4 u16 (a*21)
        uint32_t b4 = *(const uint32_t*)&Xs2[tj * 512 + p];   // 4 u8
        const unsigned short* T1 = &Ts1h[ti * TBSTRIDE];
        const unsigned short* T2 = &Ts2h[tj * TBSTRIDE];
        uint64_t outw = 0;
#pragma unroll
        for (int u = 0; u < 4; ++u) {
            int idx = (int)((a4 >> (16 * u)) & 0xFFFFu) + (int)((b4 >> (8 * u)) & 0xFFu);
            float v = b2f(T1[idx]) + b2f(T2[idx]);
            outw |= (uint64_t)f2b(v) << (16 * u);
        }
        *(uint64_t*)&Sh[pr * 520 + p] = outw;
    }
    __syncthreads();

    int wid = t >> 6, lane = t & 63;
    int lr = lane & 31, hf = lane >> 5;
    int n_base = wid * 64;

    const unsigned short* Sa = &Sh[lr * 520 + hf * 8];
    const unsigned short* Bz0 = wswz + (size_t)((wid * 2 + 0) * 32) * 512 + lane * 8;
    const unsigned short* Bz1 = wswz + (size_t)((wid * 2 + 1) * 32) * 512 + lane * 8;

    f32x16 acc0, acc1;
#pragma unroll
    for (int j = 0; j < 16; ++j) { acc0[j] = 0.f; acc1[j] = 0.f; }

#pragma unroll 2
    for (int kt = 0; kt < 32; ++kt) {
        bf16x8 av = *(const bf16x8*)(Sa + kt * 16);
        bf16x8 bv0 = *(const bf16x8*)(Bz0 + kt * 512);
        bf16x8 bv1 = *(const bf16x8*)(Bz1 + kt * 512);
        acc0 = __builtin_amdgcn_mfma_f32_32x32x16_bf16(av, bv0, acc0, 0, 0, 0);
        acc1 = __builtin_amdgcn_mfma_f32_32x32x16_bf16(av, bv1, acc1, 0, 0, 0);
    }

    float prow[16];
#pragma unroll
    for (int r = 0; r < 16; ++r) {
        int row = (r & 3) + 8 * (r >> 2) + 4 * hf;
        float v = acc0[r] * b2f(Sh[row * 520 + (n_base + lr)]);
        v      += acc1[r] * b2f(Sh[row * 520 + (n_base + 32 + lr)]);
        prow[r] = v;
    }
#pragma unroll
    for (int r = 0; r < 16; ++r) {
        float v = prow[r];
        v += __shfl_xor(v, 1);
        v += __shfl_xor(v, 2);
        v += __shfl_xor(v, 4);
        v += __shfl_xor(v, 8);
        v += __shfl_xor(v, 16);
        if (lr == 0) {
            int row = (r & 3) + 8 * (r >> 2) + 4 * hf;
            Kacc[wid][row] = v;
        }
    }
    __syncthreads();

    if (t < 32) {
        float K = Kacc[0][t] + Kacc[1][t] + Kacc[2][t] + Kacc[3][t]
                + Kacc[4][t] + Kacc[5][t] + Kacc[6][t] + Kacc[7][t];
        int ti = t >> 3, tj = t & 7;
        int i = i0 + ti, j = j0 + tj;
        float a0 = Ainp[0];
        out[i * 256 + j] = a0 * a0 * K * kinv[i] * kinv[256 + j];
    }
}

// ---------------- launcher ----------------
extern "C" void kernel_launch(void* const* d_in, const int* in_sizes, int n_in,
                              void* d_out, int out_size, void* d_ws, size_t ws_size,
                              hipStream_t stream) {
    const int*   X1 = (const int*)d_in[0];
    const int*   X2 = (const int*)d_in[1];
    const float* W  = (const float*)d_in[2];
    const float* b  = (const float*)d_in[3];
    const float* wp = (const float*)d_in[4];
    const float* a  = (const float*)d_in[5];
    float* out = (float*)d_out;

    char* ws = (char*)d_ws;
    unsigned short* Tb    = (unsigned short*)(ws + 0);         //    458,752
    float*          Tdiag = (float*)(ws + 458752);             //     49,152
    float*          w32   = (float*)(ws + 507904);             //  1,048,576
    unsigned short* wswz  = (unsigned short*)(ws + 1556480);   //    524,288
    float*          kinv  = (float*)(ws + 2080768);            //      2,048
    uint8_t*        X8    = (uint8_t*)(ws + 2082816);          //    262,144
    unsigned short* Abz   = (unsigned short*)(ws + 2344960);   // 11,010,048
    unsigned short* Wbz   = (unsigned short*)(ws + 13355008);  // 57,802,752
    float*          Ep    = (float*)(ws + 71157760);           // 44,040,192 (end 115,197,952)

    prep_kernel<<<PB_TOTAL, 256, 0, stream>>>(X1, X2, W, wp, X8, w32, wswz, Wbz, Abz);
    e_mfma_v5<<<672, 256, 0, stream>>>(Abz, Wbz, Ep);
    t_kernel<<<512, 256, 0, stream>>>(Ep, b, Tb, Tdiag);
    k_kernel<<<128, 512, 0, stream>>>(X8, Tdiag, w32, kinv);
    k4_kernel<<<dim3(64, 32), 512, 0, stream>>>(X8, Tb, wswz, kinv, a, out);
}

// Round 6
// 322.654 us; speedup vs baseline: 1.1862x; 1.0147x over previous
//
#include <hip/hip_runtime.h>
#include <cstdint>
#include <cstddef>

// ---------------- types / helpers ----------------
typedef __attribute__((ext_vector_type(8))) __bf16 bf16x8;
typedef __attribute__((ext_vector_type(4))) float f32x4;
typedef __attribute__((ext_vector_type(16))) float f32x16;

__device__ __forceinline__ unsigned short f2b(float x) {
    uint32_t u = __float_as_uint(x);
    u += 0x7FFFu + ((u >> 16) & 1u);   // RNE
    return (unsigned short)(u >> 16);
}
__device__ __forceinline__ float b2f(unsigned short h) {
    return __uint_as_float(((uint32_t)h) << 16);
}

// async global->LDS, 16B per lane. LDS dest is wave-uniform base (+lane*16 by HW).
__device__ __forceinline__ void gl16(const unsigned short* g, unsigned short* l) {
    __builtin_amdgcn_global_load_lds((const __attribute__((address_space(1))) uint32_t*)g,
                                     (__attribute__((address_space(3))) uint32_t*)l, 16, 0, 0);
}

#define L_SEQ 512
#define N_AA 21
#define DDIM 128
#define NCOL 2688        // 21*128
#define NSEQ 512         // 256 + 256
#define TBSTRIDE 448     // Tb row stride (u16), 441 used
#define KTOT 10752       // 512*21
#define ZCH 8            // k-chunks (partial-slab count)
#define KBTOT 672        // 10752/16 k-subtiles
#define KBCH 84          // 672/8 k-subtiles per chunk

// block-range sizes inside prep_kernel
#define PB_WBZ   2688    // 672 kb x 4 col-windows (LDS transpose-staged)
#define PB_REPACK 1024
#define PB_WBUILD 1024
#define PB_ABZ   2688    // 16*672/4 fragments
#define PB_TOTAL (PB_WBZ + PB_REPACK + PB_WBUILD + PB_ABZ)

#define WS_PAD 684       // LDS row stride (u16) for the W tile: 8*1368B/4 % 32 == 16 -> halves on disjoint banks

// ---------------- kernel 1: fused prologue ----------------
// Independent sub-jobs, dispatched by blockIdx range:
//   [0, 2688)      : W fp32 -> Wbz bf16 fragment-swizzled, LDS-staged so BOTH the W read
//                    and the Wbz write are fully contiguous (round-5 counters: the old
//                    column-strided read capped prep at 1.85 TB/s)
//   [+1024)        : X1/X2 int32 -> X8 u8
//   [+1024)        : w32 = sigmoid(wm), wswz = bf16 MFMA-frag order
//   [+2688)        : one-hot A -> Abz bf16 fragment-swizzled (reads X1/X2)
__global__ __launch_bounds__(256) void prep_kernel(const int* X1, const int* X2,
                                                   const float* W, const float* wp,
                                                   uint8_t* X8,
                                                   float* w32, unsigned short* wswz,
                                                   unsigned short* Wbz, unsigned short* Abz) {
    __shared__ unsigned short Ws[16 * WS_PAD];   // 21.9 KB, only used by the Wbz job
    int bid = blockIdx.x;
    int t = threadIdx.x;
    if (bid < PB_WBZ) {
        int kb = bid >> 2, cw = bid & 3;         // 16 rows starting r0, 672-col window c0
        int r0 = kb * 16, c0 = cw * 672;
        // phase 1: contiguous W read (float4/lane), bf16-convert into LDS tile [16][WS_PAD]
        for (int e = t; e < 16 * 168; e += 256) {
            int ri = e / 168, c4 = e - ri * 168;
            float4 v = *(const float4*)(W + (size_t)(r0 + ri) * NCOL + c0 + c4 * 4);
            union { ushort4 q; unsigned short s[4]; } o;
            o.s[0] = f2b(v.x); o.s[1] = f2b(v.y); o.s[2] = f2b(v.z); o.s[3] = f2b(v.w);
            *(ushort4*)&Ws[ri * WS_PAD + c4 * 4] = o.q;
        }
        __syncthreads();
        // phase 2: gather fragment order from LDS, contiguous Wbz write (uint4/lane)
        for (int e = t; e < 21 * 64; e += 256) {
            int fi = e >> 6, sl = e & 63;
            int lr = sl & 31, hf = sl >> 5;
            union { uint4 q; unsigned short s[8]; } o;
#pragma unroll
            for (int j = 0; j < 8; ++j) o.s[j] = Ws[(hf * 8 + j) * WS_PAD + fi * 32 + lr];
            int cb = cw * 21 + fi;
            *(uint4*)&Wbz[((size_t)cb * KBTOT + kb) * 512 + sl * 8] = o.q;
        }
        return;
    }
    bid -= PB_WBZ;
    if (bid < PB_REPACK) {
        int e = bid * 256 + t;             // 262,144
        if (e < 131072) X8[e] = (uint8_t)X1[e];
        else            X8[e] = (uint8_t)X2[e - 131072];
        return;
    }
    bid -= PB_REPACK;
    if (bid < PB_WBUILD) {
        int e = bid * 256 + t;             // 262,144 = 512*512
        int p = e >> 9, q = e & 511;
        float x = 0.0f;
        if (p > q)      x = wp[p * (p - 1) / 2 + q];
        else if (p < q) x = wp[q * (q - 1) / 2 + p];
        float s = 1.0f / (1.0f + expf(-x));
        w32[e] = s;
        int nb = p >> 5, lr = p & 31;
        int kb = q >> 4, hf = (q >> 3) & 1, j = q & 7;
        wswz[(size_t)((nb * 32 + kb) * 512) + (hf * 32 + lr) * 8 + j] = f2b(s);
        return;
    }
    bid -= PB_WBUILD;
    {
        // Abz fragment (mb,kb): lane (hf,lr) holds onehot(X[mb*32+lr], k=kb*16+hf*8+j)
        int f = bid * 4 + (t >> 6);        // 0..10751
        int lane = t & 63, lr = lane & 31, hf = lane >> 5;
        int mb = f / KBTOT, kb = f - mb * KBTOT;
        int m = mb * 32 + lr;
        const int* Xrow = (m < 256) ? (X1 + (size_t)m * L_SEQ) : (X2 + (size_t)(m - 256) * L_SEQ);
        int k0 = kb * 16 + hf * 8;
        union { uint4 q; unsigned short s[8]; } o;
#pragma unroll
        for (int j = 0; j < 8; ++j) {
            int k = k0 + j;
            int l = k / N_AA;
            int aa = k - l * N_AA;
            o.s[j] = (Xrow[l] == aa) ? (unsigned short)0x3F80u : (unsigned short)0u;
        }
        *(uint4*)&Abz[(size_t)f * 512 + lane * 8] = o.q;
    }
}

// ---------------- kernel 2: Ep[kz] = A @ W (k-chunk partial) — LDS ring, PLAIN STORES ---
// 672 blocks (21 c x 4 m x 8 k), XCD-swizzled, 4 waves. Per K-step the block stages its
// 8 unique fragments (4 A + 4 B, 8 KB) once via global_load_lds into a 4-deep ring;
// counted vmcnt(6) keeps 3 K-steps of loads in flight across raw s_barriers.
__global__ __launch_bounds__(256, 4) void e_mfma_v5(const unsigned short* Abz, const unsigned short* Wbz, float* Ep) {
    __shared__ unsigned short lds[4 * 8 * 512];   // 4 bufs x 8 frags x 1024 B = 32 KB

    int lin = blockIdx.x;
    int s = ((lin & 7) * 84) + (lin >> 3);    // bijective XCD swizzle (672 % 8 == 0)
    int cx = s % 21;
    int rem = s / 21;                          // 0..31
    int my = rem & 3;
    int kz = rem >> 2;                         // 0..7

    int t = threadIdx.x, wid = t >> 6, lane = t & 63;
    int lr = lane & 31, hf = lane >> 5;
    int kb0 = kz * KBCH;

    // per-wave staging sources (global, per-lane addr) and LDS dests (wave-uniform)
    const unsigned short* Aw = Abz + ((size_t)((my * 4 + wid) * KBTOT + kb0)) * 512 + lane * 8;
    const unsigned short* Bw = Wbz + ((size_t)((cx * 4 + wid) * KBTOT + kb0)) * 512 + lane * 8;
    unsigned short* La = &lds[wid * 512];
    unsigned short* Lb = &lds[(4 + wid) * 512];

#define STG(buf_, kb_) do { \
        gl16(Aw + (size_t)(kb_) * 512, La + (buf_) * 4096); \
        gl16(Bw + (size_t)(kb_) * 512, Lb + (buf_) * 4096); \
    } while (0)

    int alo = (wid & 1) * 2;          // A frag slots this wave consumes
    int blo = 4 + (wid >> 1) * 2;     // B frag slots

    f32x16 acc00, acc01, acc10, acc11;
#pragma unroll
    for (int r = 0; r < 16; ++r) { acc00[r] = 0.f; acc01[r] = 0.f; acc10[r] = 0.f; acc11[r] = 0.f; }

#define COMPUTE(kb_) do { \
        const unsigned short* base = &lds[((kb_) & 3) * 4096]; \
        bf16x8 a0 = *(const bf16x8*)(base + (alo + 0) * 512 + lane * 8); \
        bf16x8 a1 = *(const bf16x8*)(base + (alo + 1) * 512 + lane * 8); \
        bf16x8 b0 = *(const bf16x8*)(base + (blo + 0) * 512 + lane * 8); \
        bf16x8 b1 = *(const bf16x8*)(base + (blo + 1) * 512 + lane * 8); \
        acc00 = __builtin_amdgcn_mfma_f32_32x32x16_bf16(a0, b0, acc00, 0, 0, 0); \
        acc01 = __builtin_amdgcn_mfma_f32_32x32x16_bf16(a0, b1, acc01, 0, 0, 0); \
        acc10 = __builtin_amdgcn_mfma_f32_32x32x16_bf16(a1, b0, acc10, 0, 0, 0); \
        acc11 = __builtin_amdgcn_mfma_f32_32x32x16_bf16(a1, b1, acc11, 0, 0, 0); \
    } while (0)

    // prologue: stage kb=0,1,2 (6 loads/wave outstanding)
    STG(0, 0); STG(1, 1); STG(2, 2);

#pragma unroll 1
    for (int kb = 0; kb < KBCH - 3; ++kb) {
        STG((kb + 3) & 3, kb + 3);                      // overwrite buffer read at kb-1 (fenced below)
        asm volatile("s_waitcnt vmcnt(6)" ::: "memory"); // own kb loads landed; 3 steps stay in flight
        __builtin_amdgcn_s_barrier();                    // all waves' kb loads landed
        __builtin_amdgcn_sched_barrier(0);
        COMPUTE(kb);
        __builtin_amdgcn_sched_barrier(0);
        __builtin_amdgcn_s_barrier();                    // all waves done reading buf[kb&3] before restage
    }
    // tail: kb = KBCH-3 .. KBCH-1 (no more staging)
    asm volatile("s_waitcnt vmcnt(4)" ::: "memory");
    __builtin_amdgcn_s_barrier();
    __builtin_amdgcn_sched_barrier(0);
    COMPUTE(KBCH - 3);
    asm volatile("s_waitcnt vmcnt(2)" ::: "memory");
    __builtin_amdgcn_s_barrier();
    __builtin_amdgcn_sched_barrier(0);
    COMPUTE(KBCH - 2);
    asm volatile("s_waitcnt vmcnt(0)" ::: "memory");
    __builtin_amdgcn_s_barrier();
    __builtin_amdgcn_sched_barrier(0);
    COMPUTE(KBCH - 1);

#undef STG
#undef COMPUTE

    int mb0 = my * 4 + (wid & 1) * 2;        // m-fragment index (32-row units)
    int cb0 = cx * 4 + (wid >> 1) * 2;       // c-fragment index (32-col units)
    float* slab = Ep + (size_t)kz * NSEQ * NCOL;
#pragma unroll
    for (int r = 0; r < 16; ++r) {
        int row = (r & 3) + 8 * (r >> 2) + 4 * hf;
        float* base = slab + (size_t)(mb0 * 32 + row) * NCOL + cb0 * 32 + lr;
        base[0] = acc00[r];
        base[32] = acc01[r];
        base[(size_t)32 * NCOL] = acc10[r];
        base[(size_t)32 * NCOL + 32] = acc11[r];
    }
}

// ---------------- kernel 3: T[n] = E[n] @ E[n]^T, E[n] = sum_z Ep[z][n] + bias --------
__global__ __launch_bounds__(256) void t_kernel(const float* Ep, const float* bvec,
                                                unsigned short* Tb, float* Tdiag) {
    __shared__ float4 Es4[21 * 33];
    int t = threadIdx.x, n = blockIdx.x;
    for (int idx = t; idx < 672; idx += 256) {          // 672 float4 = 2688 cols
        const float4* bp = (const float4*)(bvec + idx * 4);
        float4 acc = *bp;
#pragma unroll
        for (int z = 0; z < ZCH; ++z) {
            float4 v = *(const float4*)(Ep + ((size_t)z * NSEQ + n) * NCOL + idx * 4);
            acc.x += v.x; acc.y += v.y; acc.z += v.z; acc.w += v.w;
        }
        int r = idx >> 5, d = idx & 31;
        Es4[r * 33 + d] = acc;
    }
    __syncthreads();
    for (int e = t; e < 441; e += 256) {
        int r = e / 21, c = e - r * 21;
        const float4* ar = &Es4[r * 33];
        const float4* br = &Es4[c * 33];
        float s = 0.f;
#pragma unroll 8
        for (int d = 0; d < 32; ++d) {
            float4 a = ar[d], b = br[d];
            s += a.x * b.x + a.y * b.y + a.z * b.z + a.w * b.w;
        }
        Tb[(size_t)n * TBSTRIDE + e] = f2b(0.5f * s);
        if (r == c) Tdiag[n * 24 + r] = s;
    }
}

// ---------------- kernel 4: kinv — coalesced wave-per-row bilinear form ----------------
__global__ __launch_bounds__(512) void k_kernel(const uint8_t* X8, const float* Tdiag, const float* w32, float* kinv) {
    __shared__ __align__(16) float dvec[4][512];
    __shared__ float Td[4][21];
    __shared__ float wred[4][8];
    int t = threadIdx.x, n0 = blockIdx.x * 4;
    if (t < 84) Td[t / 21][t % 21] = Tdiag[(size_t)(n0 + t / 21) * 24 + (t % 21)];
    __syncthreads();
    for (int e = t; e < 2048; e += 512) {
        int nn = e >> 9, l = e & 511;
        dvec[nn][l] = Td[nn][X8[(size_t)(n0 + nn) * 512 + l]];
    }
    __syncthreads();
    int wid = t >> 6, lane = t & 63;
    int q0 = lane * 8;

    float4 dA0 = *(const float4*)&dvec[0][q0], dA1 = *(const float4*)&dvec[0][q0 + 4];
    float4 dB0 = *(const float4*)&dvec[1][q0], dB1 = *(const float4*)&dvec[1][q0 + 4];
    float4 dC0 = *(const float4*)&dvec[2][q0], dC1 = *(const float4*)&dvec[2][q0 + 4];
    float4 dD0 = *(const float4*)&dvec[3][q0], dD1 = *(const float4*)&dvec[3][q0 + 4];

    float4 rA0 = {0,0,0,0}, rA1 = {0,0,0,0}, rB0 = {0,0,0,0}, rB1 = {0,0,0,0};
    float4 rC0 = {0,0,0,0}, rC1 = {0,0,0,0}, rD0 = {0,0,0,0}, rD1 = {0,0,0,0};

#define FMA4(R, W, S) do { (R).x += (W).x * (S); (R).y += (W).y * (S); (R).z += (W).z * (S); (R).w += (W).w * (S); } while (0)
    for (int p = wid; p < 512; p += 8) {
        const float4* wr = (const float4*)(w32 + (size_t)p * 512 + q0);
        float4 w0v = wr[0], w1v = wr[1];
        float a = dvec[0][p], b = dvec[1][p], c = dvec[2][p], d = dvec[3][p];
        FMA4(rA0, w0v, a); FMA4(rA1, w1v, a);
        FMA4(rB0, w0v, b); FMA4(rB1, w1v, b);
        FMA4(rC0, w0v, c); FMA4(rC1, w1v, c);
        FMA4(rD0, w0v, d); FMA4(rD1, w1v, d);
    }
#undef FMA4

#define DOT8(R0, R1, D0, D1) ((R0).x*(D0).x + (R0).y*(D0).y + (R0).z*(D0).z + (R0).w*(D0).w + \
                              (R1).x*(D1).x + (R1).y*(D1).y + (R1).z*(D1).z + (R1).w*(D1).w)
    float s0 = DOT8(rA0, rA1, dA0, dA1);
    float s1 = DOT8(rB0, rB1, dB0, dB1);
    float s2 = DOT8(rC0, rC1, dC0, dC1);
    float s3 = DOT8(rD0, rD1, dD0, dD1);
#undef DOT8

#pragma unroll
    for (int off = 1; off < 64; off <<= 1) {
        s0 += __shfl_xor(s0, off);
        s1 += __shfl_xor(s1, off);
        s2 += __shfl_xor(s2, off);
        s3 += __shfl_xor(s3, off);
    }
    if (lane == 0) { wred[0][wid] = s0; wred[1][wid] = s1; wred[2][wid] = s2; wred[3][wid] = s3; }
    __syncthreads();
    if (t < 4) {
        float kk = 0.f;
#pragma unroll
        for (int w = 0; w < 8; ++w) kk += wred[t][w];
        kinv[n0 + t] = 1.0f / sqrtf(kk);
    }
}

// ---------------- kernel 5: main pair GEMM — 8 waves (512 thr), bf16 Tb staging ----------
__global__ __launch_bounds__(512, 6) void k4_kernel(const uint8_t* X8, const unsigned short* Tb,
                                                    const unsigned short* wswz, const float* kinv,
                                                    const float* Ainp, float* out) {
    __shared__ unsigned short Sh[32 * 520];
    __shared__ unsigned short Ts1h[4 * TBSTRIDE];
    __shared__ unsigned short Ts2h[8 * TBSTRIDE];
    __shared__ unsigned short A21[4 * 512];
    __shared__ uint8_t Xs2[8 * 512];
    __shared__ float Kacc[8][32];

    int t = threadIdx.x;
    int i0 = blockIdx.x * 4;
    int j0 = blockIdx.y * 8;

    for (int e = t; e < 4 * 512; e += 512)
        A21[e] = (unsigned short)(21 * X8[(size_t)(i0 + (e >> 9)) * 512 + (e & 511)]);
    {
        const uint32_t* s2 = (const uint32_t*)(X8 + (size_t)(256 + j0) * 512);
        uint32_t* d2 = (uint32_t*)Xs2;
        for (int e = t; e < 1024; e += 512) d2[e] = s2[e];
    }
    {
        // Tb rows are already 0.5*T in bf16 — straight u32 copies (448 u16 = 224 u32 per row)
        uint32_t* d1 = (uint32_t*)Ts1h;
        for (int e = t; e < 4 * 224; e += 512) {
            int r = e / 224, w = e - r * 224;
            d1[e] = ((const uint32_t*)(Tb + (size_t)(i0 + r) * TBSTRIDE))[w];
        }
        uint32_t* d2 = (uint32_t*)Ts2h;
        for (int e = t; e < 8 * 224; e += 512) {
            int r = e / 224, w = e - r * 224;
            d2[e] = ((const uint32_t*)(Tb + (size_t)(256 + j0 + r) * TBSTRIDE))[w];
        }
    }
    __syncthreads();

    // build S tile: 4 elems per thread-iter, packed u64 write
    for (int e4 = t; e4 < 32 * 128; e4 += 512) {
        int pr = e4 >> 7, p = (e4 & 127) * 4;
        int ti = pr >> 3, tj = pr & 7;
        uint64_t a4 = *(const uint64_t*)&A21[ti * 512 + p];   // 4 u16 (a*21)
        uint32_t b4 = *(const uint32_t*)&Xs2[tj * 512 + p];   // 4 u8
        const unsigned short* T1 = &Ts1h[ti * TBSTRIDE];
        const unsigned short* T2 = &Ts2h[tj * TBSTRIDE];
        uint64_t outw = 0;
#pragma unroll
        for (int u = 0; u < 4; ++u) {
            int idx = (int)((a4 >> (16 * u)) & 0xFFFFu) + (int)((b4 >> (8 * u)) & 0xFFu);
            float v = b2f(T1[idx]) + b2f(T2[idx]);
            outw |= (uint64_t)f2b(v) << (16 * u);
        }
        *(uint64_t*)&Sh[pr * 520 + p] = outw;
    }
    __syncthreads();

    int wid = t >> 6, lane = t & 63;
    int lr = lane & 31, hf = lane >> 5;
    int n_base = wid * 64;

    const unsigned short* Sa = &Sh[lr * 520 + hf * 8];
    const unsigned short* Bz0 = wswz + (size_t)((wid * 2 + 0) * 32) * 512 + lane * 8;
    const unsigned short* Bz1 = wswz + (size_t)((wid * 2 + 1) * 32) * 512 + lane * 8;

    f32x16 acc0, acc1;
#pragma unroll
    for (int j = 0; j < 16; ++j) { acc0[j] = 0.f; acc1[j] = 0.f; }

#pragma unroll 2
    for (int kt = 0; kt < 32; ++kt) {
        bf16x8 av = *(const bf16x8*)(Sa + kt * 16);
        bf16x8 bv0 = *(const bf16x8*)(Bz0 + kt * 512);
        bf16x8 bv1 = *(const bf16x8*)(Bz1 + kt * 512);
        acc0 = __builtin_amdgcn_mfma_f32_32x32x16_bf16(av, bv0, acc0, 0, 0, 0);
        acc1 = __builtin_amdgcn_mfma_f32_32x32x16_bf16(av, bv1, acc1, 0, 0, 0);
    }

    float prow[16];
#pragma unroll
    for (int r = 0; r < 16; ++r) {
        int row = (r & 3) + 8 * (r >> 2) + 4 * hf;
        float v = acc0[r] * b2f(Sh[row * 520 + (n_base + lr)]);
        v      += acc1[r] * b2f(Sh[row * 520 + (n_base + 32 + lr)]);
        prow[r] = v;
    }
#pragma unroll
    for (int r = 0; r < 16; ++r) {
        float v = prow[r];
        v += __shfl_xor(v, 1);
        v += __shfl_xor(v, 2);
        v += __shfl_xor(v, 4);
        v += __shfl_xor(v, 8);
        v += __shfl_xor(v, 16);
        if (lr == 0) {
            int row = (r & 3) + 8 * (r >> 2) + 4 * hf;
            Kacc[wid][row] = v;
        }
    }
    __syncthreads();

    if (t < 32) {
        float K = Kacc[0][t] + Kacc[1][t] + Kacc[2][t] + Kacc[3][t]
                + Kacc[4][t] + Kacc[5][t] + Kacc[6][t] + Kacc[7][t];
        int ti = t >> 3, tj = t & 7;
        int i = i0 + ti, j = j0 + tj;
        float a0 = Ainp[0];
        out[i * 256 + j] = a0 * a0 * K * kinv[i] * kinv[256 + j];
    }
}

// ---------------- launcher ----------------
extern "C" void kernel_launch(void* const* d_in, const int* in_sizes, int n_in,
                              void* d_out, int out_size, void* d_ws, size_t ws_size,
                              hipStream_t stream) {
    const int*   X1 = (const int*)d_in[0];
    const int*   X2 = (const int*)d_in[1];
    const float* W  = (const float*)d_in[2];
    const float* b  = (const float*)d_in[3];
    const float* wp = (const float*)d_in[4];
    const float* a  = (const float*)d_in[5];
    float* out = (float*)d_out;

    char* ws = (char*)d_ws;
    unsigned short* Tb    = (unsigned short*)(ws + 0);         //    458,752
    float*          Tdiag = (float*)(ws + 458752);             //     49,152
    float*          w32   = (float*)(ws + 507904);             //  1,048,576
    unsigned short* wswz  = (unsigned short*)(ws + 1556480);   //    524,288
    float*          kinv  = (float*)(ws + 2080768);            //      2,048
    uint8_t*        X8    = (uint8_t*)(ws + 2082816);          //    262,144
    unsigned short* Abz   = (unsigned short*)(ws + 2344960);   // 11,010,048
    unsigned short* Wbz   = (unsigned short*)(ws + 13355008);  // 57,802,752
    float*          Ep    = (float*)(ws + 71157760);           // 44,040,192 (end 115,197,952)

    prep_kernel<<<PB_TOTAL, 256, 0, stream>>>(X1, X2, W, wp, X8, w32, wswz, Wbz, Abz);
    e_mfma_v5<<<672, 256, 0, stream>>>(Abz, Wbz, Ep);
    t_kernel<<<512, 256, 0, stream>>>(Ep, b, Tb, Tdiag);
    k_kernel<<<128, 512, 0, stream>>>(X8, Tdiag, w32, kinv);
    k4_kernel<<<dim3(64, 32), 512, 0, stream>>>(X8, Tb, wswz, kinv, a, out);
}